// Round 3
// baseline (439.285 us; speedup 1.0000x reference)
//
#include <hip/hip_runtime.h>
#include <stdint.h>

#define HD 128
#define EPS 1e-5f

// bf16 pack/unpack (RNE), explicit bit layout: low ushort = even col.
__device__ inline unsigned bf_round(float f) {
  unsigned u = __float_as_uint(f);
  return (u + 0x7fffu + ((u >> 16) & 1u)) >> 16;
}
__device__ inline unsigned bf_pack2(float x, float y) {
  return bf_round(x) | (bf_round(y) << 16);
}
__device__ inline float2 bf_unpack2(unsigned u) {
  float2 r;
  r.x = __uint_as_float(u << 16);
  r.y = __uint_as_float(u & 0xffff0000u);
  return r;
}

// ---------------- degree histogram (for dinv + rowptr) ----------------
__global__ void k_hist_dst(const int* __restrict__ dst, int* __restrict__ cnt, int E) {
  int i = blockIdx.x * blockDim.x + threadIdx.x;
  int stride = gridDim.x * blockDim.x;
  for (; i < E; i += stride) atomicAdd(&cnt[dst[i]], 1);
}

__global__ void k_dinv(const int* __restrict__ cnt, float* __restrict__ dinv, int N) {
  int i = blockIdx.x * blockDim.x + threadIdx.x;
  if (i < N) dinv[i] = rsqrtf((float)cnt[i] + 1.0f);  // +1 self-loop; always > 0
}

// ---------------- rowptr scan (over N) ----------------
__global__ __launch_bounds__(256) void k_scan1(const int* __restrict__ cnt, int* __restrict__ rowptr,
                                               int* __restrict__ bsums, int N) {
  __shared__ int lds[256];
  const int t = threadIdx.x;
  int base = blockIdx.x * 2048 + t * 8;
  int v[8]; int s = 0;
#pragma unroll
  for (int i = 0; i < 8; ++i) { int idx = base + i; v[i] = (idx < N) ? cnt[idx] : 0; s += v[i]; }
  lds[t] = s; __syncthreads();
  for (int off = 1; off < 256; off <<= 1) {
    int tv = (t >= off) ? lds[t - off] : 0;
    __syncthreads();
    lds[t] += tv;
    __syncthreads();
  }
  if (t == 255) bsums[blockIdx.x] = lds[255];
  int run = lds[t] - s;  // exclusive prefix for this thread's chunk
#pragma unroll
  for (int i = 0; i < 8; ++i) { int idx = base + i; if (idx < N) rowptr[idx] = run; run += v[i]; }
}

__global__ __launch_bounds__(256) void k_scan2(int* __restrict__ bsums, int nb) {
  __shared__ int lds[256];
  const int t = threadIdx.x;
  int v = (t < nb) ? bsums[t] : 0;
  lds[t] = v; __syncthreads();
  for (int off = 1; off < 256; off <<= 1) {
    int tv = (t >= off) ? lds[t - off] : 0;
    __syncthreads();
    lds[t] += tv;
    __syncthreads();
  }
  if (t < nb) bsums[t] = lds[t] - v;  // exclusive
}

__global__ void k_scan3(int* __restrict__ rowptr, const int* __restrict__ bsums, int N, int E) {
  int i = blockIdx.x * blockDim.x + threadIdx.x;
  if (i < N) rowptr[i] += bsums[i >> 11];
  else if (i == N) rowptr[N] = E;
}

// ---------------- bucket binning CSR build ----------------
// buckets of 32 nodes (bucket = dst>>5); NB = ceil(N/32) <= 4096 supported.
__global__ __launch_bounds__(256) void k_bhist(const int* __restrict__ dst, int* __restrict__ bcnt,
                                               int E, int NB) {
  __shared__ int h[4096];
  for (int i = threadIdx.x; i < NB; i += 256) h[i] = 0;
  __syncthreads();
  for (int i = blockIdx.x * 256 + threadIdx.x; i < E; i += gridDim.x * 256)
    atomicAdd(&h[dst[i] >> 5], 1);
  __syncthreads();
  for (int i = threadIdx.x; i < NB; i += 256) {
    int v = h[i];
    if (v) atomicAdd(&bcnt[i], v);
  }
}

__global__ __launch_bounds__(512) void k_bscan(const int* __restrict__ bcnt, int* __restrict__ bstart,
                                               int NB, int E) {
  __shared__ int lds[512];
  const int t = threadIdx.x;
  int base = t * 8;
  int v[8]; int s = 0;
#pragma unroll
  for (int i = 0; i < 8; ++i) { int idx = base + i; v[i] = (idx < NB) ? bcnt[idx] : 0; s += v[i]; }
  lds[t] = s; __syncthreads();
  for (int off = 1; off < 512; off <<= 1) {
    int tv = (t >= off) ? lds[t - off] : 0;
    __syncthreads();
    lds[t] += tv;
    __syncthreads();
  }
  int run = lds[t] - s;
#pragma unroll
  for (int i = 0; i < 8; ++i) { int idx = base + i; if (idx < NB) bstart[idx] = run; run += v[i]; }
  if (t == 511) bstart[NB] = E;
}

// append edges into bucket segments; position from per-bucket counter => sequential writes.
__global__ void k_binscatter(const int* __restrict__ src, const int* __restrict__ dst,
                             const int* __restrict__ bstart, int* __restrict__ bfill,
                             unsigned* __restrict__ bedges, int E) {
  int i = blockIdx.x * blockDim.x + threadIdx.x;
  int stride = gridDim.x * blockDim.x;
  for (; i < E; i += stride) {
    int s = src[i], d = dst[i];
    int b = d >> 5;
    int pos = atomicAdd(&bfill[b], 1);
    bedges[bstart[b] + pos] = ((unsigned)s << 7) | (unsigned)(d & 127);
  }
}

// one workgroup per 128 nodes (= 4 buckets, contiguous in bedges);
// exact placement via LDS position table; colidx writes land in a ~4KB hot window.
__global__ __launch_bounds__(256) void k_bplace(const unsigned* __restrict__ bedges,
                                                const int* __restrict__ bstart,
                                                const int* __restrict__ rowptr,
                                                unsigned short* __restrict__ colidx,
                                                int N, int NB) {
  __shared__ int pos[128];
  const int g = blockIdx.x;
  if (threadIdx.x < 128) {
    int node = g * 128 + threadIdx.x;
    pos[threadIdx.x] = (node < N) ? rowptr[node] : 0;
  }
  __syncthreads();
  int b0 = g * 4;
  int b1 = b0 + 4; if (b1 > NB) b1 = NB;
  int ee = bstart[b1];
  for (int e = bstart[b0] + threadIdx.x; e < ee; e += 256) {
    unsigned u = bedges[e];
    int p = atomicAdd(&pos[u & 127], 1);
    colidx[p] = (unsigned short)(u >> 7);
  }
}

// ---------------- GEMM: Yp[r] = bf16( dinv[r] * (bnrelu?(A[r]) @ W) ) ----------------
#define SA_LD 132  // pad 128->132: A broadcast reads become 2-way conflicts (free), float4-alignable
__global__ __launch_bounds__(512) void k_gemm(const float* __restrict__ A, const float* __restrict__ W,
                                              unsigned* __restrict__ Yp, int N,
                                              const float* __restrict__ dinv,
                                              const float* __restrict__ scale,
                                              const float* __restrict__ shift) {
  __shared__ float sW[HD * HD];      // 64 KB
  __shared__ float sA[128 * SA_LD];  // 66 KB
  const int tid = threadIdx.x;
  const int row0 = blockIdx.x * 128;
  for (int i = tid * 4; i < HD * HD; i += 512 * 4) {
    *(float4*)&sW[i] = *(const float4*)&W[i];
  }
  for (int i = tid * 4; i < 128 * HD; i += 512 * 4) {
    int r = row0 + (i >> 7);
    int c = i & 127;
    float4 v = make_float4(0.f, 0.f, 0.f, 0.f);
    if (r < N) v = *(const float4*)&A[(size_t)r * HD + c];
    if (scale) {  // fused BN+ReLU on the input tile (layer 2)
      v.x = fmaxf(0.f, v.x * scale[c + 0] + shift[c + 0]);
      v.y = fmaxf(0.f, v.y * scale[c + 1] + shift[c + 1]);
      v.z = fmaxf(0.f, v.z * scale[c + 2] + shift[c + 2]);
      v.w = fmaxf(0.f, v.w * scale[c + 3] + shift[c + 3]);
    }
    *(float4*)&sA[(i >> 7) * SA_LD + c] = v;
  }
  __syncthreads();
  const int c0 = (tid & 15) * 4;   // cols c0..c0+3 and c0+64..c0+67
  const int r0 = (tid >> 4) * 4;   // rows r0..r0+3
  float acc[4][8] = {};
#pragma unroll 4
  for (int k = 0; k < HD; ++k) {
    float av[4];
#pragma unroll
    for (int i = 0; i < 4; ++i) av[i] = sA[(r0 + i) * SA_LD + k];
    float4 w0 = *(const float4*)&sW[k * HD + c0];
    float4 w1 = *(const float4*)&sW[k * HD + c0 + 64];
    float wv[8] = {w0.x, w0.y, w0.z, w0.w, w1.x, w1.y, w1.z, w1.w};
#pragma unroll
    for (int i = 0; i < 4; ++i)
#pragma unroll
      for (int j = 0; j < 8; ++j) acc[i][j] = fmaf(av[i], wv[j], acc[i][j]);
  }
  for (int i = 0; i < 4; ++i) {
    int r = row0 + r0 + i;
    if (r >= N) continue;
    float d = dinv[r];
    uint2 p0, p1;
    p0.x = bf_pack2(acc[i][0] * d, acc[i][1] * d);
    p0.y = bf_pack2(acc[i][2] * d, acc[i][3] * d);
    p1.x = bf_pack2(acc[i][4] * d, acc[i][5] * d);
    p1.y = bf_pack2(acc[i][6] * d, acc[i][7] * d);
    *(uint2*)&Yp[(size_t)r * 64 + (c0 >> 1)] = p0;
    *(uint2*)&Yp[(size_t)r * 64 + ((c0 + 64) >> 1)] = p1;
  }
}

// ---------------- aggregate: Out[n] = dinv[n]*(Yp[n] + sum_{s in N(n)} Yp[s]) ----------------
__global__ __launch_bounds__(256) void k_aggregate(const unsigned* __restrict__ Yp,
                                                   const int* __restrict__ rowptr,
                                                   const unsigned short* __restrict__ colidx,
                                                   const float* __restrict__ dinv,
                                                   float* __restrict__ Out, int N) {
  int n = (blockIdx.x * blockDim.x + threadIdx.x) >> 6;  // one wave per node
  int lane = threadIdx.x & 63;
  if (n >= N) return;
  const int beg = rowptr[n];
  const int deg = rowptr[n + 1] - beg;
  const int m = deg < 64 ? deg : 64;
  int nbr = (lane < deg) ? (int)colidx[beg + lane] : 0;
  float2 self = bf_unpack2(Yp[(size_t)n * 64 + lane]);
  float ax = self.x, ay = self.y;
  int j = 0;
  for (; j + 4 <= m; j += 4) {
    int s0 = __shfl(nbr, j, 64);
    int s1 = __shfl(nbr, j + 1, 64);
    int s2 = __shfl(nbr, j + 2, 64);
    int s3 = __shfl(nbr, j + 3, 64);
    unsigned u0 = Yp[(size_t)s0 * 64 + lane];
    unsigned u1 = Yp[(size_t)s1 * 64 + lane];
    unsigned u2 = Yp[(size_t)s2 * 64 + lane];
    unsigned u3 = Yp[(size_t)s3 * 64 + lane];
    float2 v0 = bf_unpack2(u0), v1 = bf_unpack2(u1);
    float2 v2 = bf_unpack2(u2), v3 = bf_unpack2(u3);
    ax += (v0.x + v1.x) + (v2.x + v3.x);
    ay += (v0.y + v1.y) + (v2.y + v3.y);
  }
  for (; j < m; ++j) {
    int s0 = __shfl(nbr, j, 64);
    float2 v0 = bf_unpack2(Yp[(size_t)s0 * 64 + lane]);
    ax += v0.x; ay += v0.y;
  }
  // rare tail: degree > 64
  for (int e = beg + 64; e < beg + deg; ++e) {
    float2 v0 = bf_unpack2(Yp[(size_t)colidx[e] * 64 + lane]);
    ax += v0.x; ay += v0.y;
  }
  float dd = dinv[n];
  float2 o; o.x = ax * dd; o.y = ay * dd;
  *(float2*)&Out[(size_t)n * HD + lane * 2] = o;
}

// ---------------- per-column sum / sumsq ----------------
__global__ __launch_bounds__(256) void k_colstats(const float* __restrict__ X, int N,
                                                  float* __restrict__ sums) {
  const int c = threadIdx.x & 127;
  const int half = threadIdx.x >> 7;
  float s = 0.f, q = 0.f;
  for (int r = blockIdx.x * 2 + half; r < N; r += gridDim.x * 2) {
    float v = X[(size_t)r * HD + c];
    s += v; q += v * v;
  }
  __shared__ float ls[256], lq[256];
  ls[threadIdx.x] = s; lq[threadIdx.x] = q;
  __syncthreads();
  if (threadIdx.x < 128) {
    atomicAdd(&sums[c], ls[threadIdx.x] + ls[threadIdx.x + 128]);
    atomicAdd(&sums[128 + c], lq[threadIdx.x] + lq[threadIdx.x + 128]);
  }
}

__global__ void k_bnparams(const float* __restrict__ sums, float invN,
                           const float* __restrict__ gamma, const float* __restrict__ beta,
                           float* __restrict__ scale, float* __restrict__ shift) {
  int c = threadIdx.x;
  if (c < HD) {
    float mean = sums[c] * invN;
    float var = sums[HD + c] * invN - mean * mean;
    float sc = gamma[c] * rsqrtf(var + EPS);
    scale[c] = sc;
    shift[c] = beta[c] - mean * sc;  // note: linear bias b cancels in BN (mean-subtracted)
  }
}

__global__ void k_ghist(const int* __restrict__ batch, int* __restrict__ gcnt, int N) {
  int i = blockIdx.x * blockDim.x + threadIdx.x;
  int stride = gridDim.x * blockDim.x;
  for (; i < N; i += stride) atomicAdd(&gcnt[batch[i]], 1);
}

// ---------------- fused BN2+ReLU+dot(Wout)+pool-scatter ----------------
__global__ __launch_bounds__(256) void k_finalnode(const float* __restrict__ Agg,
                                                   const float* __restrict__ scale,
                                                   const float* __restrict__ shift,
                                                   const float* __restrict__ wout,
                                                   const int* __restrict__ batch,
                                                   float* __restrict__ gsum, int N) {
  int n = (blockIdx.x * blockDim.x + threadIdx.x) >> 6;
  int lane = threadIdx.x & 63;
  if (n >= N) return;
  int c = lane * 2;
  float2 v = *(const float2*)&Agg[(size_t)n * HD + c];
  float h0 = fmaxf(0.f, v.x * scale[c] + shift[c]);
  float h1 = fmaxf(0.f, v.y * scale[c + 1] + shift[c + 1]);
  float p = h0 * wout[c] + h1 * wout[c + 1];
  for (int off = 32; off > 0; off >>= 1) p += __shfl_down(p, off);
  if (lane == 0) atomicAdd(&gsum[batch[n]], p);
}

__global__ void k_finalout(const float* __restrict__ gsum, const int* __restrict__ gcnt,
                           const float* __restrict__ bout, float* __restrict__ out, int G) {
  int g = blockIdx.x * blockDim.x + threadIdx.x;
  if (g < G) out[g] = gsum[g] / fmaxf((float)gcnt[g], 1.0f) + bout[0];
}

extern "C" void kernel_launch(void* const* d_in, const int* in_sizes, int n_in,
                              void* d_out, int out_size, void* d_ws, size_t ws_size,
                              hipStream_t stream) {
  (void)n_in; (void)ws_size;
  const float* x      = (const float*)d_in[0];
  const int*   ei     = (const int*)d_in[1];
  const int*   batch  = (const int*)d_in[2];
  const float* W1     = (const float*)d_in[3];
  const float* gamma1 = (const float*)d_in[5];
  const float* beta1  = (const float*)d_in[6];
  const float* W2     = (const float*)d_in[7];
  const float* gamma2 = (const float*)d_in[9];
  const float* beta2  = (const float*)d_in[10];
  const float* wout   = (const float*)d_in[11];
  const float* bout   = (const float*)d_in[12];
  float* out = (float*)d_out;

  const int N = in_sizes[0] / HD;
  const int E = in_sizes[1] / 2;
  const int G = out_size;
  const int* src = ei;
  const int* dst = ei + E;
  const int NB = (N + 31) >> 5;  // 32-node buckets

  char* p = (char*)d_ws;
  auto carve = [&](size_t bytes) { char* r = p; p += (bytes + 255) & ~(size_t)255; return r; };
  unsigned* bufY = (unsigned*)carve((size_t)N * 64 * 4);   // bf16-packed Y' [N,128]
  float* bufAgg  = (float*)carve((size_t)N * HD * 4);
  unsigned* bedges = (unsigned*)carve((size_t)E * 4);
  unsigned short* colidx = (unsigned short*)carve((size_t)E * 2);
  int*   rowptr  = (int*)carve((size_t)(N + 1) * 4);
  int*   bstart  = (int*)carve((size_t)(NB + 1) * 4);
  float* dinv    = (float*)carve((size_t)N * 4);
  float* scale1  = (float*)carve(HD * 4);
  float* shift1  = (float*)carve(HD * 4);
  float* scale2  = (float*)carve(HD * 4);
  float* shift2  = (float*)carve(HD * 4);
  char* z0 = p;  // ---- zero-initialized region ----
  int*   cnt   = (int*)carve((size_t)N * 4);
  int*   bcnt  = (int*)carve((size_t)NB * 4);
  int*   bfill = (int*)carve((size_t)NB * 4);
  float* sums1 = (float*)carve(256 * 4);
  float* sums2 = (float*)carve(256 * 4);
  float* gsum  = (float*)carve((size_t)G * 4);
  int*   gcnt  = (int*)carve((size_t)G * 4);
  int*   bsums = (int*)carve(256 * 4);
  size_t zbytes = (size_t)(p - z0);

  hipMemsetAsync(z0, 0, zbytes, stream);

  // CSR build (shared by both conv layers)
  k_hist_dst<<<1024, 256, 0, stream>>>(dst, cnt, E);
  k_dinv<<<(N + 255) / 256, 256, 0, stream>>>(cnt, dinv, N);
  int nb = (N + 2047) / 2048;
  k_scan1<<<nb, 256, 0, stream>>>(cnt, rowptr, bsums, N);
  k_scan2<<<1, 256, 0, stream>>>(bsums, nb);
  k_scan3<<<(N + 1 + 255) / 256, 256, 0, stream>>>(rowptr, bsums, N, E);
  k_bhist<<<256, 256, 0, stream>>>(dst, bcnt, E, NB);
  k_bscan<<<1, 512, 0, stream>>>(bcnt, bstart, NB, E);
  k_binscatter<<<1024, 256, 0, stream>>>(src, dst, bstart, bfill, bedges, E);
  k_bplace<<<(N + 127) / 128, 256, 0, stream>>>(bedges, bstart, rowptr, colidx, N, NB);

  int gblocks = (N + 127) / 128;
  int ablocks = (N + 3) / 4;
  // layer 1
  k_gemm<<<gblocks, 512, 0, stream>>>(x, W1, bufY, N, dinv, nullptr, nullptr);
  k_aggregate<<<ablocks, 256, 0, stream>>>(bufY, rowptr, colidx, dinv, bufAgg, N);
  k_colstats<<<512, 256, 0, stream>>>(bufAgg, N, sums1);
  k_bnparams<<<1, 128, 0, stream>>>(sums1, 1.0f / (float)N, gamma1, beta1, scale1, shift1);
  // layer 2 (BN1+ReLU fused into GEMM2 input staging)
  k_gemm<<<gblocks, 512, 0, stream>>>(bufAgg, W2, bufY, N, dinv, scale1, shift1);
  k_aggregate<<<ablocks, 256, 0, stream>>>(bufY, rowptr, colidx, dinv, bufAgg, N);
  k_colstats<<<512, 256, 0, stream>>>(bufAgg, N, sums2);
  k_bnparams<<<1, 128, 0, stream>>>(sums2, 1.0f / (float)N, gamma2, beta2, scale2, shift2);
  // pooling + output head (BN2+ReLU+proj fused, h2 never materialized)
  k_ghist<<<256, 256, 0, stream>>>(batch, gcnt, N);
  k_finalnode<<<ablocks, 256, 0, stream>>>(bufAgg, scale2, shift2, wout, batch, gsum, N);
  k_finalout<<<(G + 255) / 256, 256, 0, stream>>>(gsum, gcnt, bout, out, G);
}

// Round 4
// 284.276 us; speedup vs baseline: 1.5453x; 1.5453x over previous
//
#include <hip/hip_runtime.h>
#include <stdint.h>

#define HD 128
#define EPS 1e-5f
#define NPB 256           // nodes per bucket (dst-local fits 8 bits)
#define SENT 0xFFFFFFFFu

// bf16 pack/unpack (RNE), explicit bit layout: low ushort = even col.
__device__ inline unsigned bf_round(float f) {
  unsigned u = __float_as_uint(f);
  return (u + 0x7fffu + ((u >> 16) & 1u)) >> 16;
}
__device__ inline unsigned bf_pack2(float x, float y) {
  return bf_round(x) | (bf_round(y) << 16);
}
__device__ inline float2 bf_unpack2(unsigned u) {
  float2 r;
  r.x = __uint_as_float(u << 16);
  r.y = __uint_as_float(u & 0xffff0000u);
  return r;
}

// ---------------- Phase A: bucket-bin edges with per-wg line reservation ----------------
// bline[b*16] counters are 64B apart (no same-line atomic pileup: R3 lesson).
// Each wg reserves whole 16-slot lines => every 64B arena line written by ONE wg (one XCD).
__global__ __launch_bounds__(256) void k_phaseA(const int* __restrict__ src, const int* __restrict__ dst,
                                                int* __restrict__ bline, unsigned* __restrict__ arena,
                                                int E, int NBKT, int capLines, int chunk) {
  __shared__ int hist[NPB], gbase[NPB], ccap[NPB], lpos[NPB];
  const int t = threadIdx.x;
  for (int i = t; i < NPB; i += 256) { hist[i] = 0; lpos[i] = 0; }
  __syncthreads();
  const int e0 = blockIdx.x * chunk;
  const int e1 = (e0 + chunk < E) ? e0 + chunk : E;
  // pass 1: local histogram over buckets
  for (int i = e0 + t; i < e1; i += 256) atomicAdd(&hist[dst[i] >> 8], 1);
  __syncthreads();
  // reserve lines per bucket (padded global counters)
  for (int b = t; b < NBKT; b += 256) {
    int n = hist[b];
    int nl = (n + 15) >> 4;
    int base = nl ? atomicAdd(&bline[b * 16], nl) : 0;
    if (base + nl > capLines) nl = (base < capLines) ? capLines - base : 0;  // never in practice
    gbase[b] = b * capLines * 16 + base * 16;
    ccap[b] = nl * 16;
  }
  __syncthreads();
  // pass 2: place edges into our exclusive lines
  for (int i = e0 + t; i < e1; i += 256) {
    int d = dst[i];
    int b = d >> 8;
    int lp = atomicAdd(&lpos[b], 1);
    if (lp < ccap[b]) arena[gbase[b] + lp] = ((unsigned)src[i] << 8) | (unsigned)(d & 255);
  }
  __syncthreads();
  // sentinel-pad the tail of each bucket's last line
  for (int b = t; b < NBKT; b += 256) {
    int n = lpos[b] < ccap[b] ? lpos[b] : ccap[b];
    for (int j = n; j < ccap[b]; ++j) arena[gbase[b] + j] = SENT;
  }
}

// ---------------- Phase B: per-bucket CSR finalize (deg, local scan, place) ----------------
// Also produces nodeinfo=(colidx_off<<8)|deg and dinv -- replaces hist/dinv/scan kernels.
__global__ __launch_bounds__(256) void k_phaseB(const unsigned* __restrict__ arena,
                                                const int* __restrict__ bline,
                                                unsigned short* __restrict__ colidx,
                                                unsigned* __restrict__ nodeinfo,
                                                float* __restrict__ dinv,
                                                int N, int capLines) {
  __shared__ int deg[NPB], pos[NPB], scan[NPB];
  const int b = blockIdx.x;
  const int t = threadIdx.x;
  deg[t] = 0;
  __syncthreads();
  int used = bline[b * 16];
  if (used > capLines) used = capLines;
  const int slots = used * 16;
  const unsigned* seg = arena + (size_t)b * capLines * 16;
  for (int s = t; s < slots; s += 256) {
    unsigned u = seg[s];
    if (u != SENT) atomicAdd(&deg[u & 255], 1);
  }
  __syncthreads();
  // exclusive scan of deg[256]
  int v = deg[t];
  scan[t] = v;
  __syncthreads();
  for (int off = 1; off < 256; off <<= 1) {
    int tv = (t >= off) ? scan[t - off] : 0;
    __syncthreads();
    scan[t] += tv;
    __syncthreads();
  }
  int prefix = scan[t] - v;  // exclusive
  pos[t] = prefix;
  int n = b * NPB + t;
  if (n < N) {
    unsigned off = (unsigned)(b * capLines * 16 + prefix);
    unsigned d8 = (unsigned)(v < 255 ? v : 255);
    nodeinfo[n] = (off << 8) | d8;
    dinv[n] = rsqrtf((float)v + 1.0f);
  }
  __syncthreads();
  unsigned short* cseg = colidx + (size_t)b * capLines * 16;
  for (int s = t; s < slots; s += 256) {
    unsigned u = seg[s];
    if (u != SENT) {
      int p = atomicAdd(&pos[u & 255], 1);
      cseg[p] = (unsigned short)(u >> 8);
    }
  }
}

// ---------------- GEMM: Yp[r] = bf16( dinv[r] * (bnrelu?(A[r]) @ W) ) ----------------
#define SA_LD 132
__global__ __launch_bounds__(512) void k_gemm(const float* __restrict__ A, const float* __restrict__ W,
                                              unsigned* __restrict__ Yp, int N,
                                              const float* __restrict__ dinv,
                                              const float* __restrict__ scale,
                                              const float* __restrict__ shift) {
  __shared__ float sW[HD * HD];
  __shared__ float sA[128 * SA_LD];
  const int tid = threadIdx.x;
  const int row0 = blockIdx.x * 128;
  for (int i = tid * 4; i < HD * HD; i += 512 * 4) {
    *(float4*)&sW[i] = *(const float4*)&W[i];
  }
  for (int i = tid * 4; i < 128 * HD; i += 512 * 4) {
    int r = row0 + (i >> 7);
    int c = i & 127;
    float4 v = make_float4(0.f, 0.f, 0.f, 0.f);
    if (r < N) v = *(const float4*)&A[(size_t)r * HD + c];
    if (scale) {
      v.x = fmaxf(0.f, v.x * scale[c + 0] + shift[c + 0]);
      v.y = fmaxf(0.f, v.y * scale[c + 1] + shift[c + 1]);
      v.z = fmaxf(0.f, v.z * scale[c + 2] + shift[c + 2]);
      v.w = fmaxf(0.f, v.w * scale[c + 3] + shift[c + 3]);
    }
    *(float4*)&sA[(i >> 7) * SA_LD + c] = v;
  }
  __syncthreads();
  const int c0 = (tid & 15) * 4;
  const int r0 = (tid >> 4) * 4;
  float acc[4][8] = {};
#pragma unroll 4
  for (int k = 0; k < HD; ++k) {
    float av[4];
#pragma unroll
    for (int i = 0; i < 4; ++i) av[i] = sA[(r0 + i) * SA_LD + k];
    float4 w0 = *(const float4*)&sW[k * HD + c0];
    float4 w1 = *(const float4*)&sW[k * HD + c0 + 64];
    float wv[8] = {w0.x, w0.y, w0.z, w0.w, w1.x, w1.y, w1.z, w1.w};
#pragma unroll
    for (int i = 0; i < 4; ++i)
#pragma unroll
      for (int j = 0; j < 8; ++j) acc[i][j] = fmaf(av[i], wv[j], acc[i][j]);
  }
  for (int i = 0; i < 4; ++i) {
    int r = row0 + r0 + i;
    if (r >= N) continue;
    float d = dinv[r];
    uint2 p0, p1;
    p0.x = bf_pack2(acc[i][0] * d, acc[i][1] * d);
    p0.y = bf_pack2(acc[i][2] * d, acc[i][3] * d);
    p1.x = bf_pack2(acc[i][4] * d, acc[i][5] * d);
    p1.y = bf_pack2(acc[i][6] * d, acc[i][7] * d);
    *(uint2*)&Yp[(size_t)r * 64 + (c0 >> 1)] = p0;
    *(uint2*)&Yp[(size_t)r * 64 + ((c0 + 64) >> 1)] = p1;
  }
}

// ---------------- aggregate: Out[n] = dinv[n]*(Yp[n] + sum_{s in N(n)} Yp[s]) ----------------
__global__ __launch_bounds__(256) void k_aggregate(const unsigned* __restrict__ Yp,
                                                   const unsigned* __restrict__ nodeinfo,
                                                   const unsigned short* __restrict__ colidx,
                                                   const float* __restrict__ dinv,
                                                   float* __restrict__ Out, int N) {
  int n = (blockIdx.x * blockDim.x + threadIdx.x) >> 6;  // one wave per node
  int lane = threadIdx.x & 63;
  if (n >= N) return;
  const unsigned info = nodeinfo[n];
  const int beg = (int)(info >> 8);
  const int deg = (int)(info & 255);
  const int m = deg < 64 ? deg : 64;
  int nbr = (lane < deg) ? (int)colidx[beg + lane] : 0;
  float2 self = bf_unpack2(Yp[(size_t)n * 64 + lane]);
  float ax = self.x, ay = self.y;
  int j = 0;
  for (; j + 4 <= m; j += 4) {
    int s0 = __shfl(nbr, j, 64);
    int s1 = __shfl(nbr, j + 1, 64);
    int s2 = __shfl(nbr, j + 2, 64);
    int s3 = __shfl(nbr, j + 3, 64);
    unsigned u0 = Yp[(size_t)s0 * 64 + lane];
    unsigned u1 = Yp[(size_t)s1 * 64 + lane];
    unsigned u2 = Yp[(size_t)s2 * 64 + lane];
    unsigned u3 = Yp[(size_t)s3 * 64 + lane];
    float2 v0 = bf_unpack2(u0), v1 = bf_unpack2(u1);
    float2 v2 = bf_unpack2(u2), v3 = bf_unpack2(u3);
    ax += (v0.x + v1.x) + (v2.x + v3.x);
    ay += (v0.y + v1.y) + (v2.y + v3.y);
  }
  for (; j < m; ++j) {
    int s0 = __shfl(nbr, j, 64);
    float2 v0 = bf_unpack2(Yp[(size_t)s0 * 64 + lane]);
    ax += v0.x; ay += v0.y;
  }
  for (int e = beg + 64; e < beg + deg; ++e) {  // rare: deg > 64
    float2 v0 = bf_unpack2(Yp[(size_t)colidx[e] * 64 + lane]);
    ax += v0.x; ay += v0.y;
  }
  float dd = dinv[n];
  float2 o; o.x = ax * dd; o.y = ay * dd;
  *(float2*)&Out[(size_t)n * HD + lane * 2] = o;
}

// ---------------- per-column sum / sumsq ----------------
__global__ __launch_bounds__(256) void k_colstats(const float* __restrict__ X, int N,
                                                  float* __restrict__ sums) {
  const int c = threadIdx.x & 127;
  const int half = threadIdx.x >> 7;
  float s = 0.f, q = 0.f;
  for (int r = blockIdx.x * 2 + half; r < N; r += gridDim.x * 2) {
    float v = X[(size_t)r * HD + c];
    s += v; q += v * v;
  }
  __shared__ float ls[256], lq[256];
  ls[threadIdx.x] = s; lq[threadIdx.x] = q;
  __syncthreads();
  if (threadIdx.x < 128) {
    atomicAdd(&sums[c], ls[threadIdx.x] + ls[threadIdx.x + 128]);
    atomicAdd(&sums[128 + c], lq[threadIdx.x] + lq[threadIdx.x + 128]);
  }
}

__global__ void k_bnparams(const float* __restrict__ sums, float invN,
                           const float* __restrict__ gamma, const float* __restrict__ beta,
                           float* __restrict__ scale, float* __restrict__ shift) {
  int c = threadIdx.x;
  if (c < HD) {
    float mean = sums[c] * invN;
    float var = sums[HD + c] * invN - mean * mean;
    float sc = gamma[c] * rsqrtf(var + EPS);
    scale[c] = sc;
    shift[c] = beta[c] - mean * sc;  // linear bias b cancels in BN
  }
}

// ---------------- fused BN2+ReLU+dot(Wout)+pool-scatter ----------------
__global__ __launch_bounds__(256) void k_finalnode(const float* __restrict__ Agg,
                                                   const float* __restrict__ scale,
                                                   const float* __restrict__ shift,
                                                   const float* __restrict__ wout,
                                                   const int* __restrict__ batch,
                                                   float* __restrict__ gsum, int N) {
  int n = (blockIdx.x * blockDim.x + threadIdx.x) >> 6;
  int lane = threadIdx.x & 63;
  if (n >= N) return;
  int c = lane * 2;
  float2 v = *(const float2*)&Agg[(size_t)n * HD + c];
  float h0 = fmaxf(0.f, v.x * scale[c] + shift[c]);
  float h1 = fmaxf(0.f, v.y * scale[c + 1] + shift[c + 1]);
  float p = h0 * wout[c] + h1 * wout[c + 1];
  for (int off = 32; off > 0; off >>= 1) p += __shfl_down(p, off);
  if (lane == 0) atomicAdd(&gsum[batch[n]], p);
}

// counts via binary search on sorted batch (replaces k_ghist)
__global__ void k_finalout(const float* __restrict__ gsum, const int* __restrict__ batch,
                           const float* __restrict__ bout, float* __restrict__ out,
                           int G, int N) {
  int g = blockIdx.x * blockDim.x + threadIdx.x;
  if (g >= G) return;
  int lo = 0, hi = N;  // first index with batch[i] >= g
  while (lo < hi) { int mid = (lo + hi) >> 1; if (batch[mid] < g) lo = mid + 1; else hi = mid; }
  int lb = lo;
  hi = N;              // first index with batch[i] > g
  while (lo < hi) { int mid = (lo + hi) >> 1; if (batch[mid] <= g) lo = mid + 1; else hi = mid; }
  float cnt = (float)(lo - lb);
  out[g] = gsum[g] / fmaxf(cnt, 1.0f) + bout[0];
}

extern "C" void kernel_launch(void* const* d_in, const int* in_sizes, int n_in,
                              void* d_out, int out_size, void* d_ws, size_t ws_size,
                              hipStream_t stream) {
  (void)n_in; (void)ws_size;
  const float* x      = (const float*)d_in[0];
  const int*   ei     = (const int*)d_in[1];
  const int*   batch  = (const int*)d_in[2];
  const float* W1     = (const float*)d_in[3];
  const float* gamma1 = (const float*)d_in[5];
  const float* beta1  = (const float*)d_in[6];
  const float* W2     = (const float*)d_in[7];
  const float* gamma2 = (const float*)d_in[9];
  const float* beta2  = (const float*)d_in[10];
  const float* wout   = (const float*)d_in[11];
  const float* bout   = (const float*)d_in[12];
  float* out = (float*)d_out;

  const int N = in_sizes[0] / HD;
  const int E = in_sizes[1] / 2;
  const int G = out_size;
  const int* src = ei;
  const int* dst = ei + E;
  const int NBKT = (N + NPB - 1) / NPB;
  const int NWGA = 128;
  const int chunk = (E + NWGA - 1) / NWGA;
  // capLines: avg lines/bucket = E/(NBKT*16) + NWGA/2 (rounding) + margin
  const int capLines = E / (NBKT * 16) + NWGA / 2 + 96;
  const int capSlots = capLines * 16;

  char* p = (char*)d_ws;
  auto carve = [&](size_t bytes) { char* r = p; p += (bytes + 255) & ~(size_t)255; return r; };
  unsigned* bufY = (unsigned*)carve((size_t)N * 64 * 4);     // bf16-packed Y' [N,128]
  float* bufAgg  = (float*)carve((size_t)N * HD * 4);
  unsigned* arena = (unsigned*)carve((size_t)NBKT * capSlots * 4);
  unsigned short* colidx = (unsigned short*)carve((size_t)NBKT * capSlots * 2);
  unsigned* nodeinfo = (unsigned*)carve((size_t)N * 4);
  float* dinv    = (float*)carve((size_t)N * 4);
  float* scale1  = (float*)carve(HD * 4);
  float* shift1  = (float*)carve(HD * 4);
  float* scale2  = (float*)carve(HD * 4);
  float* shift2  = (float*)carve(HD * 4);
  char* z0 = p;  // ---- zero-initialized region ----
  int*   bline = (int*)carve((size_t)NBKT * 16 * 4);  // padded: one counter per 64B line
  float* sums1 = (float*)carve(256 * 4);
  float* sums2 = (float*)carve(256 * 4);
  float* gsum  = (float*)carve((size_t)G * 4);
  size_t zbytes = (size_t)(p - z0);

  hipMemsetAsync(z0, 0, zbytes, stream);

  // CSR build (2 kernels)
  k_phaseA<<<NWGA, 256, 0, stream>>>(src, dst, bline, arena, E, NBKT, capLines, chunk);
  k_phaseB<<<NBKT, 256, 0, stream>>>(arena, bline, colidx, nodeinfo, dinv, N, capLines);

  int gblocks = (N + 127) / 128;
  int ablocks = (N + 3) / 4;
  // layer 1
  k_gemm<<<gblocks, 512, 0, stream>>>(x, W1, bufY, N, dinv, nullptr, nullptr);
  k_aggregate<<<ablocks, 256, 0, stream>>>(bufY, nodeinfo, colidx, dinv, bufAgg, N);
  k_colstats<<<512, 256, 0, stream>>>(bufAgg, N, sums1);
  k_bnparams<<<1, 128, 0, stream>>>(sums1, 1.0f / (float)N, gamma1, beta1, scale1, shift1);
  // layer 2 (BN1+ReLU fused into GEMM2 input staging)
  k_gemm<<<gblocks, 512, 0, stream>>>(bufAgg, W2, bufY, N, dinv, scale1, shift1);
  k_aggregate<<<ablocks, 256, 0, stream>>>(bufY, nodeinfo, colidx, dinv, bufAgg, N);
  k_colstats<<<512, 256, 0, stream>>>(bufAgg, N, sums2);
  k_bnparams<<<1, 128, 0, stream>>>(sums2, 1.0f / (float)N, gamma2, beta2, scale2, shift2);
  // pooling + output head
  k_finalnode<<<ablocks, 256, 0, stream>>>(bufAgg, scale2, shift2, wout, batch, gsum, N);
  k_finalout<<<(G + 255) / 256, 256, 0, stream>>>(gsum, batch, bout, out, G, N);
}

// Round 5
// 260.302 us; speedup vs baseline: 1.6876x; 1.0921x over previous
//
#include <hip/hip_runtime.h>
#include <stdint.h>

#define HD 128
#define EPS 1e-5f
#define NPB 256           // nodes per bucket (dst-local fits 8 bits)
#define SENT 0xFFFFFFFFu

typedef __attribute__((ext_vector_type(8))) short bf16x8;
typedef __attribute__((ext_vector_type(4))) float f32x4;

// bf16 pack/unpack (RNE), explicit bit layout: low ushort = even col.
__device__ inline unsigned bf_round(float f) {
  unsigned u = __float_as_uint(f);
  return (u + 0x7fffu + ((u >> 16) & 1u)) >> 16;
}
__device__ inline float2 bf_unpack2(unsigned u) {
  float2 r;
  r.x = __uint_as_float(u << 16);
  r.y = __uint_as_float(u & 0xffff0000u);
  return r;
}

// ---------------- Phase A: bucket-bin edges with per-wg line reservation ----------------
__global__ __launch_bounds__(256) void k_phaseA(const int* __restrict__ src, const int* __restrict__ dst,
                                                int* __restrict__ bline, unsigned* __restrict__ arena,
                                                int E, int NBKT, int capLines, int chunk) {
  __shared__ int hist[NPB], gbase[NPB], ccap[NPB], lpos[NPB];
  const int t = threadIdx.x;
  for (int i = t; i < NPB; i += 256) { hist[i] = 0; lpos[i] = 0; }
  __syncthreads();
  const int e0 = blockIdx.x * chunk;
  const int e1 = (e0 + chunk < E) ? e0 + chunk : E;
  for (int i = e0 + t; i < e1; i += 256) atomicAdd(&hist[dst[i] >> 8], 1);
  __syncthreads();
  for (int b = t; b < NBKT; b += 256) {
    int n = hist[b];
    int nl = (n + 15) >> 4;
    int base = nl ? atomicAdd(&bline[b * 16], nl) : 0;
    if (base + nl > capLines) nl = (base < capLines) ? capLines - base : 0;
    gbase[b] = b * capLines * 16 + base * 16;
    ccap[b] = nl * 16;
  }
  __syncthreads();
  for (int i = e0 + t; i < e1; i += 256) {
    int d = dst[i];
    int b = d >> 8;
    int lp = atomicAdd(&lpos[b], 1);
    if (lp < ccap[b]) arena[gbase[b] + lp] = ((unsigned)src[i] << 8) | (unsigned)(d & 255);
  }
  __syncthreads();
  for (int b = t; b < NBKT; b += 256) {
    int n = lpos[b] < ccap[b] ? lpos[b] : ccap[b];
    for (int j = n; j < ccap[b]; ++j) arena[gbase[b] + j] = SENT;
  }
}

// ---------------- Phase B: per-bucket CSR finalize ----------------
__global__ __launch_bounds__(256) void k_phaseB(const unsigned* __restrict__ arena,
                                                const int* __restrict__ bline,
                                                unsigned short* __restrict__ colidx,
                                                unsigned* __restrict__ nodeinfo,
                                                float* __restrict__ dinv,
                                                int N, int capLines) {
  __shared__ int deg[NPB], pos[NPB], scan[NPB];
  const int b = blockIdx.x;
  const int t = threadIdx.x;
  deg[t] = 0;
  __syncthreads();
  int used = bline[b * 16];
  if (used > capLines) used = capLines;
  const int slots = used * 16;
  const unsigned* seg = arena + (size_t)b * capLines * 16;
  for (int s = t; s < slots; s += 256) {
    unsigned u = seg[s];
    if (u != SENT) atomicAdd(&deg[u & 255], 1);
  }
  __syncthreads();
  int v = deg[t];
  scan[t] = v;
  __syncthreads();
  for (int off = 1; off < 256; off <<= 1) {
    int tv = (t >= off) ? scan[t - off] : 0;
    __syncthreads();
    scan[t] += tv;
    __syncthreads();
  }
  int prefix = scan[t] - v;  // exclusive
  pos[t] = prefix;
  int n = b * NPB + t;
  if (n < N) {
    unsigned off = (unsigned)(b * capLines * 16 + prefix);
    unsigned d8 = (unsigned)(v < 255 ? v : 255);
    nodeinfo[n] = (off << 8) | d8;
    dinv[n] = rsqrtf((float)v + 1.0f);
  }
  __syncthreads();
  unsigned short* cseg = colidx + (size_t)b * capLines * 16;
  for (int s = t; s < slots; s += 256) {
    unsigned u = seg[s];
    if (u != SENT) {
      int p = atomicAdd(&pos[u & 255], 1);
      cseg[p] = (unsigned short)(u >> 8);
    }
  }
}

// ---------------- MFMA GEMM: Yp[r] = bf16( dinv[r] * (bnrelu?(A[r]) @ W) ) ----------------
// 256 thr = 4 waves, BM=64 rows/block. W staged transposed bf16 [col][k]; A staged bf16 [row][k].
// mfma_f32_16x16x32_bf16: A-frag A[lane&15][8*(lane>>4)+i], B-frag B[k][lane&15],
// D row=4*(lane>>4)+j, col=lane&15 (m89-verified layouts).
#define SAB_LD 136  // bf16 elems; 272B rows: 16B-aligned, <=2-way LDS bank aliasing (free)
__global__ __launch_bounds__(256) void k_gemm(const float* __restrict__ A, const float* __restrict__ W,
                                              unsigned* __restrict__ Yp, int N,
                                              const float* __restrict__ dinv,
                                              const float* __restrict__ scale,
                                              const float* __restrict__ shift) {
  __shared__ unsigned short sWt[128 * SAB_LD];  // 34.8 KB, [col][k]
  __shared__ unsigned short sAb[64 * SAB_LD];   // 17.4 KB, [row][k]
  const int tid = threadIdx.x;
  const int row0 = blockIdx.x * 64;
  // stage W transposed -> bf16
  for (int i = tid * 4; i < 128 * 128; i += 256 * 4) {
    int k = i >> 7, c = i & 127;
    float4 v = *(const float4*)&W[i];
    sWt[(c + 0) * SAB_LD + k] = (unsigned short)bf_round(v.x);
    sWt[(c + 1) * SAB_LD + k] = (unsigned short)bf_round(v.y);
    sWt[(c + 2) * SAB_LD + k] = (unsigned short)bf_round(v.z);
    sWt[(c + 3) * SAB_LD + k] = (unsigned short)bf_round(v.w);
  }
  // stage A tile -> bf16 (BN+ReLU fused for layer 2)
  for (int i = tid * 4; i < 64 * 128; i += 256 * 4) {
    int r = i >> 7, c = i & 127;
    int gr = row0 + r;
    float4 v = make_float4(0.f, 0.f, 0.f, 0.f);
    if (gr < N) v = *(const float4*)&A[(size_t)gr * HD + c];
    if (scale) {
      v.x = fmaxf(0.f, v.x * scale[c + 0] + shift[c + 0]);
      v.y = fmaxf(0.f, v.y * scale[c + 1] + shift[c + 1]);
      v.z = fmaxf(0.f, v.z * scale[c + 2] + shift[c + 2]);
      v.w = fmaxf(0.f, v.w * scale[c + 3] + shift[c + 3]);
    }
    unsigned lo = bf_round(v.x) | (bf_round(v.y) << 16);
    unsigned hi = bf_round(v.z) | (bf_round(v.w) << 16);
    *(uint2*)&sAb[r * SAB_LD + c] = make_uint2(lo, hi);
  }
  __syncthreads();
  const int w = tid >> 6;        // wave id: rows 16w..16w+15
  const int l = tid & 63;
  const int lr = l & 15;         // A row-in-tile / B,D col-in-tile
  const int lk = (l >> 4) * 8;   // k-offset base
  const unsigned short* aRow = &sAb[(w * 16 + lr) * SAB_LD];
  f32x4 acc[8];
#pragma unroll
  for (int t = 0; t < 8; ++t) acc[t] = (f32x4){0.f, 0.f, 0.f, 0.f};
#pragma unroll
  for (int kk = 0; kk < 128; kk += 32) {
    bf16x8 af = *(const bf16x8*)&aRow[kk + lk];
#pragma unroll
    for (int t = 0; t < 8; ++t) {
      bf16x8 bfr = *(const bf16x8*)&sWt[(t * 16 + lr) * SAB_LD + kk + lk];
      acc[t] = __builtin_amdgcn_mfma_f32_16x16x32_bf16(af, bfr, acc[t], 0, 0, 0);
    }
  }
  // epilogue: scale by dinv, pack bf16 pairs via lane-neighbor shfl, store u32
  const int rbase = row0 + w * 16 + (l >> 4) * 4;
#pragma unroll
  for (int j = 0; j < 4; ++j) {
    int r = rbase + j;
    float d = (r < N) ? dinv[r] : 0.f;
#pragma unroll
    for (int t = 0; t < 8; ++t) {
      float v = acc[t][j] * d;
      float vn = __shfl_xor(v, 1, 64);  // partner column (col^1), same row
      if ((lr & 1) == 0 && r < N) {
        Yp[(size_t)r * 64 + t * 8 + (lr >> 1)] = bf_round(v) | (bf_round(vn) << 16);
      }
    }
  }
}

// ---------------- aggregate: Out[n] = dinv[n]*(Yp[n] + sum_{s in N(n)} Yp[s]) ----------------
__global__ __launch_bounds__(256) void k_aggregate(const unsigned* __restrict__ Yp,
                                                   const unsigned* __restrict__ nodeinfo,
                                                   const unsigned short* __restrict__ colidx,
                                                   const float* __restrict__ dinv,
                                                   float* __restrict__ Out, int N) {
  int n = (blockIdx.x * blockDim.x + threadIdx.x) >> 6;  // one wave per node
  int lane = threadIdx.x & 63;
  if (n >= N) return;
  const unsigned info = nodeinfo[n];
  const int beg = (int)(info >> 8);
  const int deg = (int)(info & 255);
  const int m = deg < 64 ? deg : 64;
  int nbr = (lane < deg) ? (int)colidx[beg + lane] : 0;
  float2 self = bf_unpack2(Yp[(size_t)n * 64 + lane]);
  float ax = self.x, ay = self.y;
  int j = 0;
  for (; j + 8 <= m; j += 8) {  // 8 independent row-reads in flight
    unsigned u0 = Yp[(size_t)__shfl(nbr, j + 0, 64) * 64 + lane];
    unsigned u1 = Yp[(size_t)__shfl(nbr, j + 1, 64) * 64 + lane];
    unsigned u2 = Yp[(size_t)__shfl(nbr, j + 2, 64) * 64 + lane];
    unsigned u3 = Yp[(size_t)__shfl(nbr, j + 3, 64) * 64 + lane];
    unsigned u4 = Yp[(size_t)__shfl(nbr, j + 4, 64) * 64 + lane];
    unsigned u5 = Yp[(size_t)__shfl(nbr, j + 5, 64) * 64 + lane];
    unsigned u6 = Yp[(size_t)__shfl(nbr, j + 6, 64) * 64 + lane];
    unsigned u7 = Yp[(size_t)__shfl(nbr, j + 7, 64) * 64 + lane];
    float2 v0 = bf_unpack2(u0), v1 = bf_unpack2(u1), v2 = bf_unpack2(u2), v3 = bf_unpack2(u3);
    float2 v4 = bf_unpack2(u4), v5 = bf_unpack2(u5), v6 = bf_unpack2(u6), v7 = bf_unpack2(u7);
    ax += ((v0.x + v1.x) + (v2.x + v3.x)) + ((v4.x + v5.x) + (v6.x + v7.x));
    ay += ((v0.y + v1.y) + (v2.y + v3.y)) + ((v4.y + v5.y) + (v6.y + v7.y));
  }
  for (; j < m; ++j) {
    float2 v0 = bf_unpack2(Yp[(size_t)__shfl(nbr, j, 64) * 64 + lane]);
    ax += v0.x; ay += v0.y;
  }
  for (int e = beg + 64; e < beg + deg; ++e) {  // rare: deg > 64
    float2 v0 = bf_unpack2(Yp[(size_t)colidx[e] * 64 + lane]);
    ax += v0.x; ay += v0.y;
  }
  float dd = dinv[n];
  float2 o; o.x = ax * dd; o.y = ay * dd;
  *(float2*)&Out[(size_t)n * HD + lane * 2] = o;
}

// ---------------- per-column sum / sumsq ----------------
__global__ __launch_bounds__(256) void k_colstats(const float* __restrict__ X, int N,
                                                  float* __restrict__ sums) {
  const int c = threadIdx.x & 127;
  const int half = threadIdx.x >> 7;
  float s = 0.f, q = 0.f;
  for (int r = blockIdx.x * 2 + half; r < N; r += gridDim.x * 2) {
    float v = X[(size_t)r * HD + c];
    s += v; q += v * v;
  }
  __shared__ float ls[256], lq[256];
  ls[threadIdx.x] = s; lq[threadIdx.x] = q;
  __syncthreads();
  if (threadIdx.x < 128) {
    atomicAdd(&sums[c], ls[threadIdx.x] + ls[threadIdx.x + 128]);
    atomicAdd(&sums[128 + c], lq[threadIdx.x] + lq[threadIdx.x + 128]);
  }
}

__global__ void k_bnparams(const float* __restrict__ sums, float invN,
                           const float* __restrict__ gamma, const float* __restrict__ beta,
                           float* __restrict__ scale, float* __restrict__ shift) {
  int c = threadIdx.x;
  if (c < HD) {
    float mean = sums[c] * invN;
    float var = sums[HD + c] * invN - mean * mean;
    float sc = gamma[c] * rsqrtf(var + EPS);
    scale[c] = sc;
    shift[c] = beta[c] - mean * sc;  // linear bias b cancels in BN
  }
}

// ---------------- fused BN2+ReLU+dot(Wout)+pool-scatter ----------------
__global__ __launch_bounds__(256) void k_finalnode(const float* __restrict__ Agg,
                                                   const float* __restrict__ scale,
                                                   const float* __restrict__ shift,
                                                   const float* __restrict__ wout,
                                                   const int* __restrict__ batch,
                                                   float* __restrict__ gsum, int N) {
  int n = (blockIdx.x * blockDim.x + threadIdx.x) >> 6;
  int lane = threadIdx.x & 63;
  if (n >= N) return;
  int c = lane * 2;
  float2 v = *(const float2*)&Agg[(size_t)n * HD + c];
  float h0 = fmaxf(0.f, v.x * scale[c] + shift[c]);
  float h1 = fmaxf(0.f, v.y * scale[c + 1] + shift[c + 1]);
  float p = h0 * wout[c] + h1 * wout[c + 1];
  for (int off = 32; off > 0; off >>= 1) p += __shfl_down(p, off);
  if (lane == 0) atomicAdd(&gsum[batch[n]], p);
}

// counts via binary search on sorted batch
__global__ void k_finalout(const float* __restrict__ gsum, const int* __restrict__ batch,
                           const float* __restrict__ bout, float* __restrict__ out,
                           int G, int N) {
  int g = blockIdx.x * blockDim.x + threadIdx.x;
  if (g >= G) return;
  int lo = 0, hi = N;
  while (lo < hi) { int mid = (lo + hi) >> 1; if (batch[mid] < g) lo = mid + 1; else hi = mid; }
  int lb = lo;
  hi = N;
  while (lo < hi) { int mid = (lo + hi) >> 1; if (batch[mid] <= g) lo = mid + 1; else hi = mid; }
  float cnt = (float)(lo - lb);
  out[g] = gsum[g] / fmaxf(cnt, 1.0f) + bout[0];
}

extern "C" void kernel_launch(void* const* d_in, const int* in_sizes, int n_in,
                              void* d_out, int out_size, void* d_ws, size_t ws_size,
                              hipStream_t stream) {
  (void)n_in; (void)ws_size;
  const float* x      = (const float*)d_in[0];
  const int*   ei     = (const int*)d_in[1];
  const int*   batch  = (const int*)d_in[2];
  const float* W1     = (const float*)d_in[3];
  const float* gamma1 = (const float*)d_in[5];
  const float* beta1  = (const float*)d_in[6];
  const float* W2     = (const float*)d_in[7];
  const float* gamma2 = (const float*)d_in[9];
  const float* beta2  = (const float*)d_in[10];
  const float* wout   = (const float*)d_in[11];
  const float* bout   = (const float*)d_in[12];
  float* out = (float*)d_out;

  const int N = in_sizes[0] / HD;
  const int E = in_sizes[1] / 2;
  const int G = out_size;
  const int* src = ei;
  const int* dst = ei + E;
  const int NBKT = (N + NPB - 1) / NPB;
  const int NWGA = 128;
  const int chunk = (E + NWGA - 1) / NWGA;
  const int capLines = E / (NBKT * 16) + NWGA / 2 + 96;
  const int capSlots = capLines * 16;

  char* p = (char*)d_ws;
  auto carve = [&](size_t bytes) { char* r = p; p += (bytes + 255) & ~(size_t)255; return r; };
  unsigned* bufY = (unsigned*)carve((size_t)N * 64 * 4);     // bf16-packed Y' [N,128]
  float* bufAgg  = (float*)carve((size_t)N * HD * 4);
  unsigned* arena = (unsigned*)carve((size_t)NBKT * capSlots * 4);
  unsigned short* colidx = (unsigned short*)carve((size_t)NBKT * capSlots * 2);
  unsigned* nodeinfo = (unsigned*)carve((size_t)N * 4);
  float* dinv    = (float*)carve((size_t)N * 4);
  float* scale1  = (float*)carve(HD * 4);
  float* shift1  = (float*)carve(HD * 4);
  float* scale2  = (float*)carve(HD * 4);
  float* shift2  = (float*)carve(HD * 4);
  char* z0 = p;  // ---- zero-initialized region ----
  int*   bline = (int*)carve((size_t)NBKT * 16 * 4);
  float* sums1 = (float*)carve(256 * 4);
  float* sums2 = (float*)carve(256 * 4);
  float* gsum  = (float*)carve((size_t)G * 4);
  size_t zbytes = (size_t)(p - z0);

  hipMemsetAsync(z0, 0, zbytes, stream);

  // CSR build (2 kernels)
  k_phaseA<<<NWGA, 256, 0, stream>>>(src, dst, bline, arena, E, NBKT, capLines, chunk);
  k_phaseB<<<NBKT, 256, 0, stream>>>(arena, bline, colidx, nodeinfo, dinv, N, capLines);

  int gblocks = (N + 63) / 64;
  int ablocks = (N + 3) / 4;
  // layer 1
  k_gemm<<<gblocks, 256, 0, stream>>>(x, W1, bufY, N, dinv, nullptr, nullptr);
  k_aggregate<<<ablocks, 256, 0, stream>>>(bufY, nodeinfo, colidx, dinv, bufAgg, N);
  k_colstats<<<512, 256, 0, stream>>>(bufAgg, N, sums1);
  k_bnparams<<<1, 128, 0, stream>>>(sums1, 1.0f / (float)N, gamma1, beta1, scale1, shift1);
  // layer 2 (BN1+ReLU fused into GEMM2 input staging)
  k_gemm<<<gblocks, 256, 0, stream>>>(bufAgg, W2, bufY, N, dinv, scale1, shift1);
  k_aggregate<<<ablocks, 256, 0, stream>>>(bufY, nodeinfo, colidx, dinv, bufAgg, N);
  k_colstats<<<512, 256, 0, stream>>>(bufAgg, N, sums2);
  k_bnparams<<<1, 128, 0, stream>>>(sums2, 1.0f / (float)N, gamma2, beta2, scale2, shift2);
  // pooling + output head
  k_finalnode<<<ablocks, 256, 0, stream>>>(bufAgg, scale2, shift2, wout, batch, gsum, N);
  k_finalout<<<(G + 255) / 256, 256, 0, stream>>>(gsum, batch, bout, out, G, N);
}

// Round 6
// 257.316 us; speedup vs baseline: 1.7072x; 1.0116x over previous
//
#include <hip/hip_runtime.h>
#include <stdint.h>

#define HD 128
#define EPS 1e-5f
#define NPB 256           // nodes per bucket (dst-local fits 8 bits)
#define SENT 0xFFFFFFFFu

typedef __attribute__((ext_vector_type(8))) short bf16x8;
typedef __attribute__((ext_vector_type(4))) float f32x4;

// bf16 pack/unpack (RNE), explicit bit layout: low ushort = even col.
__device__ inline unsigned bf_round(float f) {
  unsigned u = __float_as_uint(f);
  return (u + 0x7fffu + ((u >> 16) & 1u)) >> 16;
}
__device__ inline unsigned bf_pack2(float x, float y) {
  return bf_round(x) | (bf_round(y) << 16);
}
__device__ inline float2 bf_unpack2(unsigned u) {
  float2 r;
  r.x = __uint_as_float(u << 16);
  r.y = __uint_as_float(u & 0xffff0000u);
  return r;
}

// ---------------- zero scratch counters (replaces pathological 41us rocclr fill) ----------------
__global__ void k_zero(int* __restrict__ bline, float* __restrict__ sums1,
                       float* __restrict__ sums2, int nbline) {
  int i = blockIdx.x * 256 + threadIdx.x;
  if (i < nbline) bline[i] = 0;
  if (i < 256) { sums1[i] = 0.f; sums2[i] = 0.f; }
}

// ---------------- Phase A: bucket-bin edges with per-wg line reservation ----------------
__global__ __launch_bounds__(256) void k_phaseA(const int* __restrict__ src, const int* __restrict__ dst,
                                                int* __restrict__ bline, unsigned* __restrict__ arena,
                                                int E, int NBKT, int capLines, int chunk) {
  __shared__ int hist[NPB], gbase[NPB], ccap[NPB], lpos[NPB];
  const int t = threadIdx.x;
  for (int i = t; i < NPB; i += 256) { hist[i] = 0; lpos[i] = 0; }
  __syncthreads();
  const int e0 = blockIdx.x * chunk;
  const int e1 = (e0 + chunk < E) ? e0 + chunk : E;
  for (int i = e0 + t; i < e1; i += 256) atomicAdd(&hist[dst[i] >> 8], 1);
  __syncthreads();
  for (int b = t; b < NBKT; b += 256) {
    int n = hist[b];
    int nl = (n + 15) >> 4;
    int base = nl ? atomicAdd(&bline[b * 16], nl) : 0;
    if (base + nl > capLines) nl = (base < capLines) ? capLines - base : 0;
    gbase[b] = b * capLines * 16 + base * 16;
    ccap[b] = nl * 16;
  }
  __syncthreads();
  for (int i = e0 + t; i < e1; i += 256) {
    int d = dst[i];
    int b = d >> 8;
    int lp = atomicAdd(&lpos[b], 1);
    if (lp < ccap[b]) arena[gbase[b] + lp] = ((unsigned)src[i] << 8) | (unsigned)(d & 255);
  }
  __syncthreads();
  for (int b = t; b < NBKT; b += 256) {
    int n = lpos[b] < ccap[b] ? lpos[b] : ccap[b];
    for (int j = n; j < ccap[b]; ++j) arena[gbase[b] + j] = SENT;
  }
}

// ---------------- Phase B: per-bucket CSR finalize ----------------
__global__ __launch_bounds__(256) void k_phaseB(const unsigned* __restrict__ arena,
                                                const int* __restrict__ bline,
                                                unsigned short* __restrict__ colidx,
                                                unsigned* __restrict__ nodeinfo,
                                                float* __restrict__ dinv,
                                                int N, int capLines) {
  __shared__ int deg[NPB], pos[NPB], scan[NPB];
  const int b = blockIdx.x;
  const int t = threadIdx.x;
  deg[t] = 0;
  __syncthreads();
  int used = bline[b * 16];
  if (used > capLines) used = capLines;
  const int slots = used * 16;
  const unsigned* seg = arena + (size_t)b * capLines * 16;
  for (int s = t; s < slots; s += 256) {
    unsigned u = seg[s];
    if (u != SENT) atomicAdd(&deg[u & 255], 1);
  }
  __syncthreads();
  int v = deg[t];
  scan[t] = v;
  __syncthreads();
  for (int off = 1; off < 256; off <<= 1) {
    int tv = (t >= off) ? scan[t - off] : 0;
    __syncthreads();
    scan[t] += tv;
    __syncthreads();
  }
  int prefix = scan[t] - v;  // exclusive
  pos[t] = prefix;
  int n = b * NPB + t;
  if (n < N) {
    unsigned off = (unsigned)(b * capLines * 16 + prefix);
    unsigned d8 = (unsigned)(v < 255 ? v : 255);
    nodeinfo[n] = (off << 8) | d8;
    dinv[n] = rsqrtf((float)v + 1.0f);
  }
  __syncthreads();
  unsigned short* cseg = colidx + (size_t)b * capLines * 16;
  for (int s = t; s < slots; s += 256) {
    unsigned u = seg[s];
    if (u != SENT) {
      int p = atomicAdd(&pos[u & 255], 1);
      cseg[p] = (unsigned short)(u >> 8);
    }
  }
}

// ---------------- MFMA GEMM: Yp[r] = bf16( dinv[r] * (bnrelu?(A[r]) @ W) ) ----------------
// A source is f32 (layer 1, Abf==null) or bf16-packed (layer 2, with fused BN+ReLU).
#define SAB_LD 136  // bf16 elems; 272B rows: 16B-aligned, <=2-way LDS bank aliasing (free)
__global__ __launch_bounds__(256) void k_gemm(const float* __restrict__ Af32,
                                              const unsigned* __restrict__ Abf,
                                              const float* __restrict__ W,
                                              unsigned* __restrict__ Yp, int N,
                                              const float* __restrict__ dinv,
                                              const float* __restrict__ scale,
                                              const float* __restrict__ shift) {
  __shared__ unsigned short sWt[128 * SAB_LD];  // 34.8 KB, [col][k]
  __shared__ unsigned short sAb[64 * SAB_LD];   // 17.4 KB, [row][k]
  const int tid = threadIdx.x;
  const int row0 = blockIdx.x * 64;
  // stage W transposed -> bf16
  for (int i = tid * 4; i < 128 * 128; i += 256 * 4) {
    int k = i >> 7, c = i & 127;
    float4 v = *(const float4*)&W[i];
    sWt[(c + 0) * SAB_LD + k] = (unsigned short)bf_round(v.x);
    sWt[(c + 1) * SAB_LD + k] = (unsigned short)bf_round(v.y);
    sWt[(c + 2) * SAB_LD + k] = (unsigned short)bf_round(v.z);
    sWt[(c + 3) * SAB_LD + k] = (unsigned short)bf_round(v.w);
  }
  // stage A tile -> bf16 (BN+ReLU fused for layer 2)
  for (int i = tid * 4; i < 64 * 128; i += 256 * 4) {
    int r = i >> 7, c = i & 127;
    int gr = row0 + r;
    float4 v = make_float4(0.f, 0.f, 0.f, 0.f);
    if (gr < N) {
      if (Abf) {
        uint2 u = *(const uint2*)&Abf[(size_t)gr * 64 + (c >> 1)];
        float2 a = bf_unpack2(u.x), bq = bf_unpack2(u.y);
        v = make_float4(a.x, a.y, bq.x, bq.y);
      } else {
        v = *(const float4*)&Af32[(size_t)gr * HD + c];
      }
    }
    if (scale) {
      v.x = fmaxf(0.f, v.x * scale[c + 0] + shift[c + 0]);
      v.y = fmaxf(0.f, v.y * scale[c + 1] + shift[c + 1]);
      v.z = fmaxf(0.f, v.z * scale[c + 2] + shift[c + 2]);
      v.w = fmaxf(0.f, v.w * scale[c + 3] + shift[c + 3]);
    }
    unsigned lo = bf_round(v.x) | (bf_round(v.y) << 16);
    unsigned hi = bf_round(v.z) | (bf_round(v.w) << 16);
    *(uint2*)&sAb[r * SAB_LD + c] = make_uint2(lo, hi);
  }
  __syncthreads();
  const int w = tid >> 6;        // wave id: rows 16w..16w+15
  const int l = tid & 63;
  const int lr = l & 15;         // A row-in-tile / B,D col-in-tile
  const int lk = (l >> 4) * 8;   // k-offset base
  const unsigned short* aRow = &sAb[(w * 16 + lr) * SAB_LD];
  f32x4 acc[8];
#pragma unroll
  for (int t = 0; t < 8; ++t) acc[t] = (f32x4){0.f, 0.f, 0.f, 0.f};
#pragma unroll
  for (int kk = 0; kk < 128; kk += 32) {
    bf16x8 af = *(const bf16x8*)&aRow[kk + lk];
#pragma unroll
    for (int t = 0; t < 8; ++t) {
      bf16x8 bfr = *(const bf16x8*)&sWt[(t * 16 + lr) * SAB_LD + kk + lk];
      acc[t] = __builtin_amdgcn_mfma_f32_16x16x32_bf16(af, bfr, acc[t], 0, 0, 0);
    }
  }
  // epilogue: scale by dinv, pack bf16 pairs via lane-neighbor shfl, store u32
  const int rbase = row0 + w * 16 + (l >> 4) * 4;
#pragma unroll
  for (int j = 0; j < 4; ++j) {
    int r = rbase + j;
    float d = (r < N) ? dinv[r] : 0.f;
#pragma unroll
    for (int t = 0; t < 8; ++t) {
      float v = acc[t][j] * d;
      float vn = __shfl_xor(v, 1, 64);  // partner column (col^1), same row
      if ((lr & 1) == 0 && r < N) {
        Yp[(size_t)r * 64 + t * 8 + (lr >> 1)] = bf_round(v) | (bf_round(vn) << 16);
      }
    }
  }
}

// ---------------- aggregate: Out[n] = bf16( dinv[n]*(Yp[n] + sum_{s in N(n)} Yp[s]) ) ----------------
__global__ __launch_bounds__(256) void k_aggregate(const unsigned* __restrict__ Yp,
                                                   const unsigned* __restrict__ nodeinfo,
                                                   const unsigned short* __restrict__ colidx,
                                                   const float* __restrict__ dinv,
                                                   unsigned* __restrict__ Out, int N) {
  int n = (blockIdx.x * blockDim.x + threadIdx.x) >> 6;  // one wave per node
  int lane = threadIdx.x & 63;
  if (n >= N) return;
  const unsigned info = nodeinfo[n];
  const int beg = (int)(info >> 8);
  const int deg = (int)(info & 255);
  const int m = deg < 64 ? deg : 64;
  int nbr = (lane < deg) ? (int)colidx[beg + lane] : 0;
  float2 self = bf_unpack2(Yp[(size_t)n * 64 + lane]);
  float ax = self.x, ay = self.y;
  int j = 0;
  for (; j + 8 <= m; j += 8) {  // 8 independent row-reads in flight
    unsigned u0 = Yp[(size_t)__shfl(nbr, j + 0, 64) * 64 + lane];
    unsigned u1 = Yp[(size_t)__shfl(nbr, j + 1, 64) * 64 + lane];
    unsigned u2 = Yp[(size_t)__shfl(nbr, j + 2, 64) * 64 + lane];
    unsigned u3 = Yp[(size_t)__shfl(nbr, j + 3, 64) * 64 + lane];
    unsigned u4 = Yp[(size_t)__shfl(nbr, j + 4, 64) * 64 + lane];
    unsigned u5 = Yp[(size_t)__shfl(nbr, j + 5, 64) * 64 + lane];
    unsigned u6 = Yp[(size_t)__shfl(nbr, j + 6, 64) * 64 + lane];
    unsigned u7 = Yp[(size_t)__shfl(nbr, j + 7, 64) * 64 + lane];
    float2 v0 = bf_unpack2(u0), v1 = bf_unpack2(u1), v2 = bf_unpack2(u2), v3 = bf_unpack2(u3);
    float2 v4 = bf_unpack2(u4), v5 = bf_unpack2(u5), v6 = bf_unpack2(u6), v7 = bf_unpack2(u7);
    ax += ((v0.x + v1.x) + (v2.x + v3.x)) + ((v4.x + v5.x) + (v6.x + v7.x));
    ay += ((v0.y + v1.y) + (v2.y + v3.y)) + ((v4.y + v5.y) + (v6.y + v7.y));
  }
  for (; j < m; ++j) {
    float2 v0 = bf_unpack2(Yp[(size_t)__shfl(nbr, j, 64) * 64 + lane]);
    ax += v0.x; ay += v0.y;
  }
  for (int e = beg + 64; e < beg + deg; ++e) {  // rare: deg > 64
    float2 v0 = bf_unpack2(Yp[(size_t)colidx[e] * 64 + lane]);
    ax += v0.x; ay += v0.y;
  }
  float dd = dinv[n];
  Out[(size_t)n * 64 + lane] = bf_pack2(ax * dd, ay * dd);
}

// ---------------- per-column sum / sumsq over bf16-packed X ----------------
__global__ __launch_bounds__(256) void k_colstats(const unsigned* __restrict__ X, int N,
                                                  float* __restrict__ sums) {
  const int c2 = threadIdx.x & 63;   // packed col pair
  const int half = threadIdx.x >> 6; // 4-way row split
  float sx = 0.f, sy = 0.f, qx = 0.f, qy = 0.f;
  for (int r = blockIdx.x * 4 + half; r < N; r += gridDim.x * 4) {
    float2 v = bf_unpack2(X[(size_t)r * 64 + c2]);
    sx += v.x; sy += v.y; qx += v.x * v.x; qy += v.y * v.y;
  }
  __shared__ float l0[256], l1[256], l2[256], l3[256];
  l0[threadIdx.x] = sx; l1[threadIdx.x] = sy; l2[threadIdx.x] = qx; l3[threadIdx.x] = qy;
  __syncthreads();
  if (threadIdx.x < 64) {
    int t = threadIdx.x;
    sx = l0[t] + l0[t + 64] + l0[t + 128] + l0[t + 192];
    sy = l1[t] + l1[t + 64] + l1[t + 128] + l1[t + 192];
    qx = l2[t] + l2[t + 64] + l2[t + 128] + l2[t + 192];
    qy = l3[t] + l3[t + 64] + l3[t + 128] + l3[t + 192];
    int c = t * 2;
    atomicAdd(&sums[c], sx);
    atomicAdd(&sums[c + 1], sy);
    atomicAdd(&sums[128 + c], qx);
    atomicAdd(&sums[129 + c], qy);
  }
}

__global__ void k_bnparams(const float* __restrict__ sums, float invN,
                           const float* __restrict__ gamma, const float* __restrict__ beta,
                           float* __restrict__ scale, float* __restrict__ shift) {
  int c = threadIdx.x;
  if (c < HD) {
    float mean = sums[c] * invN;
    float var = sums[HD + c] * invN - mean * mean;
    float sc = gamma[c] * rsqrtf(var + EPS);
    scale[c] = sc;
    shift[c] = beta[c] - mean * sc;  // linear bias b cancels in BN
  }
}

// ---------------- fused BN2+ReLU+dot(Wout) per node (atomic-free) ----------------
__global__ __launch_bounds__(256) void k_finalnode(const unsigned* __restrict__ Agg,
                                                   const float* __restrict__ scale,
                                                   const float* __restrict__ shift,
                                                   const float* __restrict__ wout,
                                                   float* __restrict__ nodescalar, int N) {
  int n = (blockIdx.x * blockDim.x + threadIdx.x) >> 6;
  int lane = threadIdx.x & 63;
  if (n >= N) return;
  int c = lane * 2;
  float2 v = bf_unpack2(Agg[(size_t)n * 64 + lane]);
  float h0 = fmaxf(0.f, v.x * scale[c] + shift[c]);
  float h1 = fmaxf(0.f, v.y * scale[c + 1] + shift[c + 1]);
  float p = h0 * wout[c] + h1 * wout[c + 1];
  for (int off = 32; off > 0; off >>= 1) p += __shfl_down(p, off);
  if (lane == 0) nodescalar[n] = p;
}

// mean over each graph's contiguous node range (batch sorted) via binary search
__global__ void k_finalout(const float* __restrict__ nodescalar, const int* __restrict__ batch,
                           const float* __restrict__ bout, float* __restrict__ out,
                           int G, int N) {
  int g = blockIdx.x * blockDim.x + threadIdx.x;
  if (g >= G) return;
  int lo = 0, hi = N;
  while (lo < hi) { int mid = (lo + hi) >> 1; if (batch[mid] < g) lo = mid + 1; else hi = mid; }
  int lb = lo;
  hi = N;
  while (lo < hi) { int mid = (lo + hi) >> 1; if (batch[mid] <= g) lo = mid + 1; else hi = mid; }
  float s = 0.f;
  for (int i = lb; i < lo; ++i) s += nodescalar[i];
  float cnt = (float)(lo - lb);
  out[g] = s / fmaxf(cnt, 1.0f) + bout[0];
}

extern "C" void kernel_launch(void* const* d_in, const int* in_sizes, int n_in,
                              void* d_out, int out_size, void* d_ws, size_t ws_size,
                              hipStream_t stream) {
  (void)n_in; (void)ws_size;
  const float* x      = (const float*)d_in[0];
  const int*   ei     = (const int*)d_in[1];
  const int*   batch  = (const int*)d_in[2];
  const float* W1     = (const float*)d_in[3];
  const float* gamma1 = (const float*)d_in[5];
  const float* beta1  = (const float*)d_in[6];
  const float* W2     = (const float*)d_in[7];
  const float* gamma2 = (const float*)d_in[9];
  const float* beta2  = (const float*)d_in[10];
  const float* wout   = (const float*)d_in[11];
  const float* bout   = (const float*)d_in[12];
  float* out = (float*)d_out;

  const int N = in_sizes[0] / HD;
  const int E = in_sizes[1] / 2;
  const int G = out_size;
  const int* src = ei;
  const int* dst = ei + E;
  const int NBKT = (N + NPB - 1) / NPB;
  const int NWGA = 128;
  const int chunk = (E + NWGA - 1) / NWGA;
  const int capLines = E / (NBKT * 16) + NWGA / 2 + 96;
  const int capSlots = capLines * 16;

  char* p = (char*)d_ws;
  auto carve = [&](size_t bytes) { char* r = p; p += (bytes + 255) & ~(size_t)255; return r; };
  unsigned* bufY = (unsigned*)carve((size_t)N * 64 * 4);     // bf16-packed Y' [N,128]
  unsigned* bufAgg = (unsigned*)carve((size_t)N * 64 * 4);   // bf16-packed Agg [N,128]
  unsigned* arena = (unsigned*)carve((size_t)NBKT * capSlots * 4);
  unsigned short* colidx = (unsigned short*)carve((size_t)NBKT * capSlots * 2);
  unsigned* nodeinfo = (unsigned*)carve((size_t)N * 4);
  float* dinv    = (float*)carve((size_t)N * 4);
  float* nodescalar = (float*)carve((size_t)N * 4);
  float* scale1  = (float*)carve(HD * 4);
  float* shift1  = (float*)carve(HD * 4);
  float* scale2  = (float*)carve(HD * 4);
  float* shift2  = (float*)carve(HD * 4);
  int*   bline = (int*)carve((size_t)NBKT * 16 * 4);
  float* sums1 = (float*)carve(256 * 4);
  float* sums2 = (float*)carve(256 * 4);

  const int nbline = NBKT * 16;
  int zblocks = (nbline + 255) / 256;
  k_zero<<<zblocks, 256, 0, stream>>>(bline, sums1, sums2, nbline);

  // CSR build (2 kernels)
  k_phaseA<<<NWGA, 256, 0, stream>>>(src, dst, bline, arena, E, NBKT, capLines, chunk);
  k_phaseB<<<NBKT, 256, 0, stream>>>(arena, bline, colidx, nodeinfo, dinv, N, capLines);

  int gblocks = (N + 63) / 64;
  int ablocks = (N + 3) / 4;
  // layer 1
  k_gemm<<<gblocks, 256, 0, stream>>>(x, nullptr, W1, bufY, N, dinv, nullptr, nullptr);
  k_aggregate<<<ablocks, 256, 0, stream>>>(bufY, nodeinfo, colidx, dinv, bufAgg, N);
  k_colstats<<<512, 256, 0, stream>>>(bufAgg, N, sums1);
  k_bnparams<<<1, 128, 0, stream>>>(sums1, 1.0f / (float)N, gamma1, beta1, scale1, shift1);
  // layer 2 (BN1+ReLU fused into GEMM2 input staging, bf16 A source)
  k_gemm<<<gblocks, 256, 0, stream>>>(nullptr, bufAgg, W2, bufY, N, dinv, scale1, shift1);
  k_aggregate<<<ablocks, 256, 0, stream>>>(bufY, nodeinfo, colidx, dinv, bufAgg, N);
  k_colstats<<<512, 256, 0, stream>>>(bufAgg, N, sums2);
  k_bnparams<<<1, 128, 0, stream>>>(sums2, 1.0f / (float)N, gamma2, beta2, scale2, shift2);
  // pooling + output head (atomic-free)
  k_finalnode<<<ablocks, 256, 0, stream>>>(bufAgg, scale2, shift2, wout, nodescalar, N);
  k_finalout<<<(G + 255) / 256, 256, 0, stream>>>(nodescalar, batch, bout, out, G, N);
}

// Round 7
// 233.554 us; speedup vs baseline: 1.8809x; 1.1017x over previous
//
#include <hip/hip_runtime.h>
#include <stdint.h>

#define HD 128
#define EPS 1e-5f
#define NPB 256           // nodes per bucket (dst-local fits 8 bits)
#define SENT 0xFFFFFFFFu

typedef __attribute__((ext_vector_type(8))) short bf16x8;
typedef __attribute__((ext_vector_type(4))) float f32x4;

// bf16 pack/unpack (RNE), explicit bit layout: low ushort = even col.
__device__ inline unsigned bf_round(float f) {
  unsigned u = __float_as_uint(f);
  return (u + 0x7fffu + ((u >> 16) & 1u)) >> 16;
}
__device__ inline unsigned bf_pack2(float x, float y) {
  return bf_round(x) | (bf_round(y) << 16);
}
__device__ inline float2 bf_unpack2(unsigned u) {
  float2 r;
  r.x = __uint_as_float(u << 16);
  r.y = __uint_as_float(u & 0xffff0000u);
  return r;
}

// ---------------- prep: W1,W2 -> bf16 transposed [col][k]; zero counters ----------------
__global__ void k_prep(const float* __restrict__ W1, const float* __restrict__ W2,
                       unsigned short* __restrict__ Wt1, unsigned short* __restrict__ Wt2,
                       int* __restrict__ bline, float* __restrict__ sums1,
                       float* __restrict__ sums2, int nbline) {
  int b = blockIdx.x, t = threadIdx.x;
  if (b < 64) {
    int e = b * 256 + t;
    int k = e >> 7, c = e & 127;
    Wt1[c * 128 + k] = (unsigned short)bf_round(W1[e]);
  } else if (b < 128) {
    int e = (b - 64) * 256 + t;
    int k = e >> 7, c = e & 127;
    Wt2[c * 128 + k] = (unsigned short)bf_round(W2[e]);
  } else {
    int i = (b - 128) * 256 + t;
    if (i < nbline) bline[i] = 0;
    if (i < 256) { sums1[i] = 0.f; sums2[i] = 0.f; }
  }
}

// ---------------- Phase A: bucket-bin edges with per-wg line reservation ----------------
__global__ __launch_bounds__(256) void k_phaseA(const int* __restrict__ src, const int* __restrict__ dst,
                                                int* __restrict__ bline, unsigned* __restrict__ arena,
                                                int E, int NBKT, int capLines, int chunk) {
  __shared__ int hist[NPB], gbase[NPB], ccap[NPB], lpos[NPB];
  const int t = threadIdx.x;
  for (int i = t; i < NPB; i += 256) { hist[i] = 0; lpos[i] = 0; }
  __syncthreads();
  const int e0 = blockIdx.x * chunk;
  const int e1 = (e0 + chunk < E) ? e0 + chunk : E;
  for (int i = e0 + t; i < e1; i += 256) atomicAdd(&hist[dst[i] >> 8], 1);
  __syncthreads();
  for (int b = t; b < NBKT; b += 256) {
    int n = hist[b];
    int nl = (n + 15) >> 4;
    int base = nl ? atomicAdd(&bline[b * 16], nl) : 0;
    if (base + nl > capLines) nl = (base < capLines) ? capLines - base : 0;
    gbase[b] = b * capLines * 16 + base * 16;
    ccap[b] = nl * 16;
  }
  __syncthreads();
  for (int i = e0 + t; i < e1; i += 256) {
    int d = dst[i];
    int b = d >> 8;
    int lp = atomicAdd(&lpos[b], 1);
    if (lp < ccap[b]) arena[gbase[b] + lp] = ((unsigned)src[i] << 8) | (unsigned)(d & 255);
  }
  __syncthreads();
  for (int b = t; b < NBKT; b += 256) {
    int n = lpos[b] < ccap[b] ? lpos[b] : ccap[b];
    for (int j = n; j < ccap[b]; ++j) arena[gbase[b] + j] = SENT;
  }
}

// ---------------- Phase B: per-bucket CSR finalize ----------------
__global__ __launch_bounds__(256) void k_phaseB(const unsigned* __restrict__ arena,
                                                const int* __restrict__ bline,
                                                unsigned short* __restrict__ colidx,
                                                unsigned* __restrict__ nodeinfo,
                                                float* __restrict__ dinv,
                                                int N, int capLines) {
  __shared__ int deg[NPB], pos[NPB], scan[NPB];
  const int b = blockIdx.x;
  const int t = threadIdx.x;
  deg[t] = 0;
  __syncthreads();
  int used = bline[b * 16];
  if (used > capLines) used = capLines;
  const int slots = used * 16;
  const unsigned* seg = arena + (size_t)b * capLines * 16;
  for (int s = t; s < slots; s += 256) {
    unsigned u = seg[s];
    if (u != SENT) atomicAdd(&deg[u & 255], 1);
  }
  __syncthreads();
  int v = deg[t];
  scan[t] = v;
  __syncthreads();
  for (int off = 1; off < 256; off <<= 1) {
    int tv = (t >= off) ? scan[t - off] : 0;
    __syncthreads();
    scan[t] += tv;
    __syncthreads();
  }
  int prefix = scan[t] - v;  // exclusive
  pos[t] = prefix;
  int n = b * NPB + t;
  if (n < N) {
    unsigned off = (unsigned)(b * capLines * 16 + prefix);
    unsigned d8 = (unsigned)(v < 255 ? v : 255);
    nodeinfo[n] = (off << 8) | d8;
    dinv[n] = rsqrtf((float)v + 1.0f);
  }
  __syncthreads();
  unsigned short* cseg = colidx + (size_t)b * capLines * 16;
  for (int s = t; s < slots; s += 256) {
    unsigned u = seg[s];
    if (u != SENT) {
      int p = atomicAdd(&pos[u & 255], 1);
      cseg[p] = (unsigned short)(u >> 8);
    }
  }
}

// ---------------- MFMA GEMM: Yp[r] = bf16( dinv[r] * (bnrelu?(A[r]) @ W) ) ----------------
// Wt is pre-transposed bf16 [col][k] in global (k_prep). If sums!=null, BN params are
// computed in-block from sums/gamma/beta (layer 2) and applied+ReLU on the A tile.
#define SAB_LD 136  // bf16 elems; 272B rows: 16B-aligned, <=2-way LDS bank aliasing (free)
__global__ __launch_bounds__(256) void k_gemm(const float* __restrict__ Af32,
                                              const unsigned* __restrict__ Abf,
                                              const unsigned short* __restrict__ Wt,
                                              unsigned* __restrict__ Yp, int N,
                                              const float* __restrict__ dinv,
                                              const float* __restrict__ sums,
                                              const float* __restrict__ gamma,
                                              const float* __restrict__ beta, float invN) {
  __shared__ unsigned short sWt[128 * SAB_LD];  // 34.8 KB, [col][k]
  __shared__ unsigned short sAb[64 * SAB_LD];   // 17.4 KB, [row][k]
  __shared__ float sSc[128], sSh[128];
  const int tid = threadIdx.x;
  const int row0 = blockIdx.x * 64;
  // stage pre-transposed W: coalesced uint4 copy (8 bf16 along k)
  for (int i = tid * 8; i < 128 * 128; i += 256 * 8) {
    int c = i >> 7, k = i & 127;
    uint4 v = *(const uint4*)&Wt[i];
    *(uint4*)&sWt[c * SAB_LD + k] = v;
  }
  // BN params (layer 2): deterministic identical compute per block
  if (sums && tid < 128) {
    float mean = sums[tid] * invN;
    float var = sums[128 + tid] * invN - mean * mean;
    float sc = gamma[tid] * rsqrtf(var + EPS);
    sSc[tid] = sc;
    sSh[tid] = beta[tid] - mean * sc;
  }
  __syncthreads();
  // stage A tile -> bf16 (BN+ReLU fused for layer 2)
  for (int i = tid * 4; i < 64 * 128; i += 256 * 4) {
    int r = i >> 7, c = i & 127;
    int gr = row0 + r;
    float4 v = make_float4(0.f, 0.f, 0.f, 0.f);
    if (gr < N) {
      if (Abf) {
        uint2 u = *(const uint2*)&Abf[(size_t)gr * 64 + (c >> 1)];
        float2 a = bf_unpack2(u.x), bq = bf_unpack2(u.y);
        v = make_float4(a.x, a.y, bq.x, bq.y);
      } else {
        v = *(const float4*)&Af32[(size_t)gr * HD + c];
      }
    }
    if (sums) {
      v.x = fmaxf(0.f, v.x * sSc[c + 0] + sSh[c + 0]);
      v.y = fmaxf(0.f, v.y * sSc[c + 1] + sSh[c + 1]);
      v.z = fmaxf(0.f, v.z * sSc[c + 2] + sSh[c + 2]);
      v.w = fmaxf(0.f, v.w * sSc[c + 3] + sSh[c + 3]);
    }
    unsigned lo = bf_round(v.x) | (bf_round(v.y) << 16);
    unsigned hi = bf_round(v.z) | (bf_round(v.w) << 16);
    *(uint2*)&sAb[r * SAB_LD + c] = make_uint2(lo, hi);
  }
  __syncthreads();
  const int w = tid >> 6;        // wave id: rows 16w..16w+15
  const int l = tid & 63;
  const int lr = l & 15;         // A row-in-tile / B,D col-in-tile
  const int lk = (l >> 4) * 8;   // k-offset base
  const unsigned short* aRow = &sAb[(w * 16 + lr) * SAB_LD];
  f32x4 acc[8];
#pragma unroll
  for (int t = 0; t < 8; ++t) acc[t] = (f32x4){0.f, 0.f, 0.f, 0.f};
#pragma unroll
  for (int kk = 0; kk < 128; kk += 32) {
    bf16x8 af = *(const bf16x8*)&aRow[kk + lk];
#pragma unroll
    for (int t = 0; t < 8; ++t) {
      bf16x8 bfr = *(const bf16x8*)&sWt[(t * 16 + lr) * SAB_LD + kk + lk];
      acc[t] = __builtin_amdgcn_mfma_f32_16x16x32_bf16(af, bfr, acc[t], 0, 0, 0);
    }
  }
  // epilogue: scale by dinv, pack bf16 pairs via lane-neighbor shfl, store u32
  const int rbase = row0 + w * 16 + (l >> 4) * 4;
#pragma unroll
  for (int j = 0; j < 4; ++j) {
    int r = rbase + j;
    float d = (r < N) ? dinv[r] : 0.f;
#pragma unroll
    for (int t = 0; t < 8; ++t) {
      float v = acc[t][j] * d;
      float vn = __shfl_xor(v, 1, 64);  // partner column (col^1), same row
      if ((lr & 1) == 0 && r < N) {
        Yp[(size_t)r * 64 + t * 8 + (lr >> 1)] = bf_round(v) | (bf_round(vn) << 16);
      }
    }
  }
}

// ---------------- aggregate: Out[n] = bf16( dinv[n]*(Yp[n] + sum_{s in N(n)} Yp[s]) ) ----------------
__global__ __launch_bounds__(256) void k_aggregate(const unsigned* __restrict__ Yp,
                                                   const unsigned* __restrict__ nodeinfo,
                                                   const unsigned short* __restrict__ colidx,
                                                   const float* __restrict__ dinv,
                                                   unsigned* __restrict__ Out, int N) {
  int n = (blockIdx.x * blockDim.x + threadIdx.x) >> 6;  // one wave per node
  int lane = threadIdx.x & 63;
  if (n >= N) return;
  const unsigned info = nodeinfo[n];
  const int beg = (int)(info >> 8);
  const int deg = (int)(info & 255);
  const int m = deg < 64 ? deg : 64;
  int nbr = (lane < deg) ? (int)colidx[beg + lane] : 0;
  float2 self = bf_unpack2(Yp[(size_t)n * 64 + lane]);
  float ax = self.x, ay = self.y;
  int j = 0;
  for (; j + 8 <= m; j += 8) {  // 8 independent row-reads in flight
    unsigned u0 = Yp[(size_t)__shfl(nbr, j + 0, 64) * 64 + lane];
    unsigned u1 = Yp[(size_t)__shfl(nbr, j + 1, 64) * 64 + lane];
    unsigned u2 = Yp[(size_t)__shfl(nbr, j + 2, 64) * 64 + lane];
    unsigned u3 = Yp[(size_t)__shfl(nbr, j + 3, 64) * 64 + lane];
    unsigned u4 = Yp[(size_t)__shfl(nbr, j + 4, 64) * 64 + lane];
    unsigned u5 = Yp[(size_t)__shfl(nbr, j + 5, 64) * 64 + lane];
    unsigned u6 = Yp[(size_t)__shfl(nbr, j + 6, 64) * 64 + lane];
    unsigned u7 = Yp[(size_t)__shfl(nbr, j + 7, 64) * 64 + lane];
    float2 v0 = bf_unpack2(u0), v1 = bf_unpack2(u1), v2 = bf_unpack2(u2), v3 = bf_unpack2(u3);
    float2 v4 = bf_unpack2(u4), v5 = bf_unpack2(u5), v6 = bf_unpack2(u6), v7 = bf_unpack2(u7);
    ax += ((v0.x + v1.x) + (v2.x + v3.x)) + ((v4.x + v5.x) + (v6.x + v7.x));
    ay += ((v0.y + v1.y) + (v2.y + v3.y)) + ((v4.y + v5.y) + (v6.y + v7.y));
  }
  for (; j < m; ++j) {
    float2 v0 = bf_unpack2(Yp[(size_t)__shfl(nbr, j, 64) * 64 + lane]);
    ax += v0.x; ay += v0.y;
  }
  for (int e = beg + 64; e < beg + deg; ++e) {  // rare: deg > 64
    float2 v0 = bf_unpack2(Yp[(size_t)colidx[e] * 64 + lane]);
    ax += v0.x; ay += v0.y;
  }
  float dd = dinv[n];
  Out[(size_t)n * 64 + lane] = bf_pack2(ax * dd, ay * dd);
}

// ---------------- per-column sum / sumsq over bf16-packed X ----------------
__global__ __launch_bounds__(256) void k_colstats(const unsigned* __restrict__ X, int N,
                                                  float* __restrict__ sums) {
  const int c2 = threadIdx.x & 63;   // packed col pair
  const int half = threadIdx.x >> 6; // 4-way row split
  float sx = 0.f, sy = 0.f, qx = 0.f, qy = 0.f;
  for (int r = blockIdx.x * 4 + half; r < N; r += gridDim.x * 4) {
    float2 v = bf_unpack2(X[(size_t)r * 64 + c2]);
    sx += v.x; sy += v.y; qx += v.x * v.x; qy += v.y * v.y;
  }
  __shared__ float l0[256], l1[256], l2[256], l3[256];
  l0[threadIdx.x] = sx; l1[threadIdx.x] = sy; l2[threadIdx.x] = qx; l3[threadIdx.x] = qy;
  __syncthreads();
  if (threadIdx.x < 64) {
    int t = threadIdx.x;
    sx = l0[t] + l0[t + 64] + l0[t + 128] + l0[t + 192];
    sy = l1[t] + l1[t + 64] + l1[t + 128] + l1[t + 192];
    qx = l2[t] + l2[t + 64] + l2[t + 128] + l2[t + 192];
    qy = l3[t] + l3[t + 64] + l3[t + 128] + l3[t + 192];
    int c = t * 2;
    atomicAdd(&sums[c], sx);
    atomicAdd(&sums[c + 1], sy);
    atomicAdd(&sums[128 + c], qx);
    atomicAdd(&sums[129 + c], qy);
  }
}

// ---------------- fused BN2+ReLU+dot(Wout) per node (atomic-free, BN params in-thread) ----------------
__global__ __launch_bounds__(256) void k_finalnode(const unsigned* __restrict__ Agg,
                                                   const float* __restrict__ sums,
                                                   const float* __restrict__ gamma,
                                                   const float* __restrict__ beta,
                                                   const float* __restrict__ wout,
                                                   float* __restrict__ nodescalar,
                                                   int N, float invN) {
  int n = (blockIdx.x * blockDim.x + threadIdx.x) >> 6;
  int lane = threadIdx.x & 63;
  if (n >= N) return;
  int c = lane * 2;
  float mean0 = sums[c] * invN;
  float var0 = sums[128 + c] * invN - mean0 * mean0;
  float sc0 = gamma[c] * rsqrtf(var0 + EPS);
  float sh0 = beta[c] - mean0 * sc0;
  float mean1 = sums[c + 1] * invN;
  float var1 = sums[129 + c] * invN - mean1 * mean1;
  float sc1 = gamma[c + 1] * rsqrtf(var1 + EPS);
  float sh1 = beta[c + 1] - mean1 * sc1;
  float2 v = bf_unpack2(Agg[(size_t)n * 64 + lane]);
  float h0 = fmaxf(0.f, v.x * sc0 + sh0);
  float h1 = fmaxf(0.f, v.y * sc1 + sh1);
  float p = h0 * wout[c] + h1 * wout[c + 1];
  for (int off = 32; off > 0; off >>= 1) p += __shfl_down(p, off);
  if (lane == 0) nodescalar[n] = p;
}

// mean over each graph's contiguous node range (batch sorted) via binary search
__global__ void k_finalout(const float* __restrict__ nodescalar, const int* __restrict__ batch,
                           const float* __restrict__ bout, float* __restrict__ out,
                           int G, int N) {
  int g = blockIdx.x * blockDim.x + threadIdx.x;
  if (g >= G) return;
  int lo = 0, hi = N;
  while (lo < hi) { int mid = (lo + hi) >> 1; if (batch[mid] < g) lo = mid + 1; else hi = mid; }
  int lb = lo;
  hi = N;
  while (lo < hi) { int mid = (lo + hi) >> 1; if (batch[mid] <= g) lo = mid + 1; else hi = mid; }
  float s = 0.f;
  for (int i = lb; i < lo; ++i) s += nodescalar[i];
  float cnt = (float)(lo - lb);
  out[g] = s / fmaxf(cnt, 1.0f) + bout[0];
}

extern "C" void kernel_launch(void* const* d_in, const int* in_sizes, int n_in,
                              void* d_out, int out_size, void* d_ws, size_t ws_size,
                              hipStream_t stream) {
  (void)n_in; (void)ws_size;
  const float* x      = (const float*)d_in[0];
  const int*   ei     = (const int*)d_in[1];
  const int*   batch  = (const int*)d_in[2];
  const float* W1     = (const float*)d_in[3];
  const float* gamma1 = (const float*)d_in[5];
  const float* beta1  = (const float*)d_in[6];
  const float* W2     = (const float*)d_in[7];
  const float* gamma2 = (const float*)d_in[9];
  const float* beta2  = (const float*)d_in[10];
  const float* wout   = (const float*)d_in[11];
  const float* bout   = (const float*)d_in[12];
  float* out = (float*)d_out;

  const int N = in_sizes[0] / HD;
  const int E = in_sizes[1] / 2;
  const int G = out_size;
  const int* src = ei;
  const int* dst = ei + E;
  const int NBKT = (N + NPB - 1) / NPB;
  const int NWGA = 256;
  const int chunk = (E + NWGA - 1) / NWGA;
  const int capLines = E / (NBKT * 16) + NWGA + 64;  // worst case: 1 partial line per wg per bucket
  const int capSlots = capLines * 16;
  const float invN = 1.0f / (float)N;

  char* p = (char*)d_ws;
  auto carve = [&](size_t bytes) { char* r = p; p += (bytes + 255) & ~(size_t)255; return r; };
  unsigned* bufY = (unsigned*)carve((size_t)N * 64 * 4);     // bf16-packed Y' [N,128]
  unsigned* bufAgg = (unsigned*)carve((size_t)N * 64 * 4);   // bf16-packed Agg [N,128]
  unsigned* arena = (unsigned*)carve((size_t)NBKT * capSlots * 4);
  unsigned short* colidx = (unsigned short*)carve((size_t)NBKT * capSlots * 2);
  unsigned short* Wt1 = (unsigned short*)carve(128 * 128 * 2);
  unsigned short* Wt2 = (unsigned short*)carve(128 * 128 * 2);
  unsigned* nodeinfo = (unsigned*)carve((size_t)N * 4);
  float* dinv    = (float*)carve((size_t)N * 4);
  float* nodescalar = (float*)carve((size_t)N * 4);
  int*   bline = (int*)carve((size_t)NBKT * 16 * 4);
  float* sums1 = (float*)carve(256 * 4);
  float* sums2 = (float*)carve(256 * 4);

  const int nbline = NBKT * 16;
  const int pblocks = 128 + (nbline + 255) / 256;
  k_prep<<<pblocks, 256, 0, stream>>>(W1, W2, Wt1, Wt2, bline, sums1, sums2, nbline);

  // CSR build (2 kernels)
  k_phaseA<<<NWGA, 256, 0, stream>>>(src, dst, bline, arena, E, NBKT, capLines, chunk);
  k_phaseB<<<NBKT, 256, 0, stream>>>(arena, bline, colidx, nodeinfo, dinv, N, capLines);

  int gblocks = (N + 63) / 64;
  int ablocks = (N + 3) / 4;
  // layer 1
  k_gemm<<<gblocks, 256, 0, stream>>>(x, nullptr, Wt1, bufY, N, dinv, nullptr, nullptr, nullptr, invN);
  k_aggregate<<<ablocks, 256, 0, stream>>>(bufY, nodeinfo, colidx, dinv, bufAgg, N);
  k_colstats<<<512, 256, 0, stream>>>(bufAgg, N, sums1);
  // layer 2 (BN1 params computed in-block from sums1; BN1+ReLU fused into A staging)
  k_gemm<<<gblocks, 256, 0, stream>>>(nullptr, bufAgg, Wt2, bufY, N, dinv, sums1, gamma1, beta1, invN);
  k_aggregate<<<ablocks, 256, 0, stream>>>(bufY, nodeinfo, colidx, dinv, bufAgg, N);
  k_colstats<<<512, 256, 0, stream>>>(bufAgg, N, sums2);
  // pooling + output head (atomic-free; BN2 params in-thread)
  k_finalnode<<<ablocks, 256, 0, stream>>>(bufAgg, sums2, gamma2, beta2, wout, nodescalar, N, invN);
  k_finalout<<<(G + 255) / 256, 256, 0, stream>>>(nodescalar, batch, bout, out, G, N);
}